// Round 1
// baseline (1242.586 us; speedup 1.0000x reference)
//
#include <hip/hip_runtime.h>

#define T_DIM   12
#define N_NODES 10000
#define F_IN    32
#define H_DIM   64
#define E_EDGES 320000

// ---------------------------------------------------------------- degree
__global__ void deg_kernel(const int* __restrict__ col,
                           const float* __restrict__ w,
                           float* __restrict__ deg, int E) {
    int e = blockIdx.x * blockDim.x + threadIdx.x;
    if (e < E) atomicAdd(&deg[col[e]], w[e]);
}

// ---------------------------------------------------------------- norm
__global__ void norm_kernel(const int* __restrict__ row,
                            const int* __restrict__ col,
                            const float* __restrict__ w,
                            const float* __restrict__ deg,
                            float* __restrict__ nrm, int E) {
    int e = blockIdx.x * blockDim.x + threadIdx.x;
    if (e >= E) return;
    float dr = deg[row[e]];
    float dc = deg[col[e]];
    float ir = dr > 0.f ? 1.0f / sqrtf(fmaxf(dr, 1e-12f)) : 0.f;
    float ic = dc > 0.f ? 1.0f / sqrtf(fmaxf(dc, 1e-12f)) : 0.f;
    nrm[e] = ir * w[e] * ic;
}

// ---------------------------------------------------------------- gemm1: y1 = x @ W1   (rows=T*N, 32 -> 64)
__global__ __launch_bounds__(256) void gemm1_kernel(const float* __restrict__ x,
                                                    const float* __restrict__ W1,
                                                    float* __restrict__ y1, int rows) {
    __shared__ float Ws[F_IN * H_DIM];  // 8 KB
    for (int i = threadIdx.x; i < F_IN * H_DIM; i += 256) Ws[i] = W1[i];
    __syncthreads();
    int r = blockIdx.x * 256 + threadIdx.x;
    if (r >= rows) return;

    float xv[F_IN];
    const float4* xp = (const float4*)(x + (size_t)r * F_IN);
#pragma unroll
    for (int i = 0; i < F_IN / 4; i++) {
        float4 v = xp[i];
        xv[4 * i + 0] = v.x; xv[4 * i + 1] = v.y; xv[4 * i + 2] = v.z; xv[4 * i + 3] = v.w;
    }
    float acc[H_DIM];
#pragma unroll
    for (int j = 0; j < H_DIM; j++) acc[j] = 0.f;
#pragma unroll
    for (int k = 0; k < F_IN; k++) {
        float xk = xv[k];
#pragma unroll
        for (int j = 0; j < H_DIM; j++) acc[j] = fmaf(xk, Ws[k * H_DIM + j], acc[j]);
    }
    float4* yp = (float4*)(y1 + (size_t)r * H_DIM);
#pragma unroll
    for (int j = 0; j < H_DIM / 4; j++)
        yp[j] = make_float4(acc[4 * j], acc[4 * j + 1], acc[4 * j + 2], acc[4 * j + 3]);
}

// ---------------------------------------------------------------- scatter1: agg1[t,col,:] += y1[t,row,:]*norm  (64 feat)
__global__ __launch_bounds__(256) void scatter1_kernel(const int* __restrict__ row,
                                                       const int* __restrict__ col,
                                                       const float* __restrict__ nrm,
                                                       const float* __restrict__ y1,
                                                       float* __restrict__ agg1, int E) {
    int eg = blockIdx.x * 4 + (threadIdx.x >> 6);
    int f  = threadIdx.x & 63;
    if (eg >= E) return;
    int   r  = row[eg];
    int   c  = col[eg];
    float nw = nrm[eg];
    const float* src = y1   + (size_t)r * H_DIM + f;
    float*       dst = agg1 + (size_t)c * H_DIM + f;
#pragma unroll
    for (int t = 0; t < T_DIM; t++) {
        size_t off = (size_t)t * N_NODES * H_DIM;
        atomicAdd(dst + off, src[off] * nw);
    }
}

// ---------------------------------------------------------------- gemm2: y2 = relu(agg1 + b1) @ W2  (64 -> 32)
__global__ __launch_bounds__(256) void gemm2_kernel(const float* __restrict__ agg1,
                                                    const float* __restrict__ b1,
                                                    const float* __restrict__ W2,
                                                    float* __restrict__ y2, int rows) {
    __shared__ float Ws[H_DIM * F_IN];  // 8 KB
    __shared__ float bs[H_DIM];
    for (int i = threadIdx.x; i < H_DIM * F_IN; i += 256) Ws[i] = W2[i];
    if (threadIdx.x < H_DIM) bs[threadIdx.x] = b1[threadIdx.x];
    __syncthreads();
    int r = blockIdx.x * 256 + threadIdx.x;
    if (r >= rows) return;

    float hv[H_DIM];
    const float4* hp = (const float4*)(agg1 + (size_t)r * H_DIM);
#pragma unroll
    for (int i = 0; i < H_DIM / 4; i++) {
        float4 v = hp[i];
        hv[4 * i + 0] = fmaxf(v.x + bs[4 * i + 0], 0.f);
        hv[4 * i + 1] = fmaxf(v.y + bs[4 * i + 1], 0.f);
        hv[4 * i + 2] = fmaxf(v.z + bs[4 * i + 2], 0.f);
        hv[4 * i + 3] = fmaxf(v.w + bs[4 * i + 3], 0.f);
    }
    float acc[F_IN];
#pragma unroll
    for (int j = 0; j < F_IN; j++) acc[j] = 0.f;
#pragma unroll
    for (int k = 0; k < H_DIM; k++) {
        float hk = hv[k];
#pragma unroll
        for (int j = 0; j < F_IN; j++) acc[j] = fmaf(hk, Ws[k * F_IN + j], acc[j]);
    }
    float4* yp = (float4*)(y2 + (size_t)r * F_IN);
#pragma unroll
    for (int j = 0; j < F_IN / 4; j++)
        yp[j] = make_float4(acc[4 * j], acc[4 * j + 1], acc[4 * j + 2], acc[4 * j + 3]);
}

// ---------------------------------------------------------------- scatter2: out[t,col,:] += y2[t,row,:]*norm  (32 feat)
__global__ __launch_bounds__(256) void scatter2_kernel(const int* __restrict__ row,
                                                       const int* __restrict__ col,
                                                       const float* __restrict__ nrm,
                                                       const float* __restrict__ y2,
                                                       float* __restrict__ out, int E) {
    int eg = blockIdx.x * 8 + (threadIdx.x >> 5);
    int f  = threadIdx.x & 31;
    if (eg >= E) return;
    int   r  = row[eg];
    int   c  = col[eg];
    float nw = nrm[eg];
    const float* src = y2  + (size_t)r * F_IN + f;
    float*       dst = out + (size_t)c * F_IN + f;
#pragma unroll
    for (int t = 0; t < T_DIM; t++) {
        size_t off = (size_t)t * N_NODES * F_IN;
        atomicAdd(dst + off, src[off] * nw);
    }
}

// ---------------------------------------------------------------- tanh epilogue: out = tanh(out + b2)
__global__ void tanh_kernel(float* __restrict__ out, const float* __restrict__ b2, int n4) {
    int i = blockIdx.x * blockDim.x + threadIdx.x;
    if (i >= n4) return;
    float4 v = ((float4*)out)[i];
    int f = (i * 4) & (F_IN - 1);
    v.x = tanhf(v.x + b2[f + 0]);
    v.y = tanhf(v.y + b2[f + 1]);
    v.z = tanhf(v.z + b2[f + 2]);
    v.w = tanhf(v.w + b2[f + 3]);
    ((float4*)out)[i] = v;
}

// ----------------------------------------------------------------
extern "C" void kernel_launch(void* const* d_in, const int* in_sizes, int n_in,
                              void* d_out, int out_size, void* d_ws, size_t ws_size,
                              hipStream_t stream) {
    const float* x   = (const float*)d_in[0];
    const int*   ei  = (const int*)d_in[1];          // (2, E) int32
    const float* w   = (const float*)d_in[2];
    // d_in[3] = missing_mask (unused by reference)
    const float* W1  = (const float*)d_in[4];
    const float* b1  = (const float*)d_in[5];
    const float* W2  = (const float*)d_in[6];
    const float* b2  = (const float*)d_in[7];
    float* out = (float*)d_out;

    const int E = in_sizes[1] / 2;
    const int* row = ei;          // edge_index[0]
    const int* col = ei + E;      // edge_index[1]

    char* ws = (char*)d_ws;
    float* deg  = (float*)(ws);                                // 40 KB
    float* nrm  = (float*)(ws + (size_t)1 * 1024 * 1024);      // 1.28 MB
    float* y1   = (float*)(ws + (size_t)3 * 1024 * 1024);      // 30.72 MB (reused as y2)
    float* agg1 = (float*)(ws + (size_t)36 * 1024 * 1024);     // 30.72 MB
    // total ~67 MB

    const int rows = T_DIM * N_NODES;

    // norm precompute
    hipMemsetAsync(deg, 0, N_NODES * sizeof(float), stream);
    deg_kernel<<<(E + 255) / 256, 256, 0, stream>>>(col, w, deg, E);
    norm_kernel<<<(E + 255) / 256, 256, 0, stream>>>(row, col, w, deg, nrm, E);

    // layer 1
    gemm1_kernel<<<(rows + 255) / 256, 256, 0, stream>>>(x, W1, y1, rows);
    hipMemsetAsync(agg1, 0, (size_t)rows * H_DIM * sizeof(float), stream);
    scatter1_kernel<<<(E + 3) / 4, 256, 0, stream>>>(row, col, nrm, y1, agg1, E);

    // layer 2 (y2 reuses y1 buffer)
    float* y2 = y1;
    gemm2_kernel<<<(rows + 255) / 256, 256, 0, stream>>>(agg1, b1, W2, y2, rows);
    hipMemsetAsync(out, 0, (size_t)out_size * sizeof(float), stream);
    scatter2_kernel<<<(E + 7) / 8, 256, 0, stream>>>(row, col, nrm, y2, out, E);

    // epilogue
    int n4 = rows * F_IN / 4;
    tanh_kernel<<<(n4 + 255) / 256, 256, 0, stream>>>(out, b2, n4);
}

// Round 2
// 256.130 us; speedup vs baseline: 4.8514x; 4.8514x over previous
//
#include <hip/hip_runtime.h>

#define T_DIM   12
#define N_NODES 10000
#define F_IN    32
#define H_DIM   64

// ------------------------------------------------ degree (float) + histogram (int), fused
__global__ void deg_hist_kernel(const int* __restrict__ col,
                                const float* __restrict__ w,
                                float* __restrict__ deg,
                                int* __restrict__ cnt, int E) {
    int e = blockIdx.x * blockDim.x + threadIdx.x;
    if (e >= E) return;
    int c = col[e];
    atomicAdd(&deg[c], w[e]);
    atomicAdd(&cnt[c], 1);
}

// ------------------------------------------------ per-edge symmetric norm
__global__ void norm_kernel(const int* __restrict__ row,
                            const int* __restrict__ col,
                            const float* __restrict__ w,
                            const float* __restrict__ deg,
                            float* __restrict__ nrm, int E) {
    int e = blockIdx.x * blockDim.x + threadIdx.x;
    if (e >= E) return;
    float dr = deg[row[e]];
    float dc = deg[col[e]];
    float ir = dr > 0.f ? 1.0f / sqrtf(fmaxf(dr, 1e-12f)) : 0.f;
    float ic = dc > 0.f ? 1.0f / sqrtf(fmaxf(dc, 1e-12f)) : 0.f;
    nrm[e] = ir * w[e] * ic;
}

// ------------------------------------------------ single-block exclusive scan -> rowptr
__global__ __launch_bounds__(1024) void scan_kernel(const int* __restrict__ cnt,
                                                    int* __restrict__ rowptr, int n) {
    __shared__ int part[1024];
    int tid = threadIdx.x;
    const int per = (n + 1023) / 1024;
    int base = tid * per;
    int s = 0;
    for (int i = 0; i < per; i++) {
        int idx = base + i;
        if (idx < n) s += cnt[idx];
    }
    part[tid] = s;
    __syncthreads();
    for (int off = 1; off < 1024; off <<= 1) {
        int v = 0;
        if (tid >= off) v = part[tid - off];
        __syncthreads();
        if (tid >= off) part[tid] += v;
        __syncthreads();
    }
    int run = (tid == 0) ? 0 : part[tid - 1];
    for (int i = 0; i < per; i++) {
        int idx = base + i;
        if (idx < n) { rowptr[idx] = run; run += cnt[idx]; }
    }
    if (tid == 1023) rowptr[n] = part[1023];
}

// ------------------------------------------------ bucket fill: sort edges by dst
__global__ void fill_kernel(const int* __restrict__ row,
                            const int* __restrict__ col,
                            const float* __restrict__ nrm,
                            const int* __restrict__ rowptr,
                            int* __restrict__ cur,
                            int* __restrict__ src_s,
                            float* __restrict__ nrm_s, int E) {
    int e = blockIdx.x * blockDim.x + threadIdx.x;
    if (e >= E) return;
    int c = col[e];
    int pos = atomicAdd(&cur[c], 1);
    int o = rowptr[c] + pos;
    src_s[o] = row[e];
    nrm_s[o] = nrm[e];
}

// ------------------------------------------------ CSR gather-aggregate over 32 features,
// all 12 time steps in registers; optionally fused tanh(acc + bias) epilogue.
template <bool TANH>
__global__ __launch_bounds__(256) void gather_agg_kernel(const int* __restrict__ rowptr,
                                                         const int* __restrict__ src_s,
                                                         const float* __restrict__ nrm_s,
                                                         const float* __restrict__ y,
                                                         const float* __restrict__ bias,
                                                         float* __restrict__ outp, int n) {
    int c = blockIdx.x * 8 + (threadIdx.x >> 5);
    int f = threadIdx.x & 31;
    if (c >= n) return;
    int beg = rowptr[c], end = rowptr[c + 1];

    float acc[T_DIM];
#pragma unroll
    for (int t = 0; t < T_DIM; t++) acc[t] = 0.f;

    for (int e = beg; e < end; e++) {
        int   s  = src_s[e];
        float nw = nrm_s[e];
        const float* sp = y + (size_t)s * F_IN + f;
#pragma unroll
        for (int t = 0; t < T_DIM; t++)
            acc[t] = fmaf(sp[(size_t)t * N_NODES * F_IN], nw, acc[t]);
    }

    float* op = outp + (size_t)c * F_IN + f;
    if (TANH) {
        float b = bias[f];
#pragma unroll
        for (int t = 0; t < T_DIM; t++)
            op[(size_t)t * N_NODES * F_IN] = tanhf(acc[t] + b);
    } else {
#pragma unroll
        for (int t = 0; t < T_DIM; t++)
            op[(size_t)t * N_NODES * F_IN] = acc[t];
    }
}

// ------------------------------------------------ gemm1: h1 = relu(agg_x @ W1 + b1)  (32 -> 64)
__global__ __launch_bounds__(256) void gemm1_kernel(const float* __restrict__ aggx,
                                                    const float* __restrict__ W1,
                                                    const float* __restrict__ b1,
                                                    float* __restrict__ h1, int rows) {
    __shared__ float Ws[F_IN * H_DIM];
    __shared__ float bs[H_DIM];
    for (int i = threadIdx.x; i < F_IN * H_DIM; i += 256) Ws[i] = W1[i];
    if (threadIdx.x < H_DIM) bs[threadIdx.x] = b1[threadIdx.x];
    __syncthreads();
    int r = blockIdx.x * 256 + threadIdx.x;
    if (r >= rows) return;

    float xv[F_IN];
    const float4* xp = (const float4*)(aggx + (size_t)r * F_IN);
#pragma unroll
    for (int i = 0; i < F_IN / 4; i++) {
        float4 v = xp[i];
        xv[4 * i + 0] = v.x; xv[4 * i + 1] = v.y; xv[4 * i + 2] = v.z; xv[4 * i + 3] = v.w;
    }
    float acc[H_DIM];
#pragma unroll
    for (int j = 0; j < H_DIM; j++) acc[j] = bs[j];
#pragma unroll
    for (int k = 0; k < F_IN; k++) {
        float xk = xv[k];
#pragma unroll
        for (int j = 0; j < H_DIM; j++) acc[j] = fmaf(xk, Ws[k * H_DIM + j], acc[j]);
    }
    float4* yp = (float4*)(h1 + (size_t)r * H_DIM);
#pragma unroll
    for (int j = 0; j < H_DIM / 4; j++)
        yp[j] = make_float4(fmaxf(acc[4 * j], 0.f), fmaxf(acc[4 * j + 1], 0.f),
                            fmaxf(acc[4 * j + 2], 0.f), fmaxf(acc[4 * j + 3], 0.f));
}

// ------------------------------------------------ gemm2: y2 = h1 @ W2  (64 -> 32, no bias)
__global__ __launch_bounds__(256) void gemm2_kernel(const float* __restrict__ h1,
                                                    const float* __restrict__ W2,
                                                    float* __restrict__ y2, int rows) {
    __shared__ float Ws[H_DIM * F_IN];
    for (int i = threadIdx.x; i < H_DIM * F_IN; i += 256) Ws[i] = W2[i];
    __syncthreads();
    int r = blockIdx.x * 256 + threadIdx.x;
    if (r >= rows) return;

    float hv[H_DIM];
    const float4* hp = (const float4*)(h1 + (size_t)r * H_DIM);
#pragma unroll
    for (int i = 0; i < H_DIM / 4; i++) {
        float4 v = hp[i];
        hv[4 * i + 0] = v.x; hv[4 * i + 1] = v.y; hv[4 * i + 2] = v.z; hv[4 * i + 3] = v.w;
    }
    float acc[F_IN];
#pragma unroll
    for (int j = 0; j < F_IN; j++) acc[j] = 0.f;
#pragma unroll
    for (int k = 0; k < H_DIM; k++) {
        float hk = hv[k];
#pragma unroll
        for (int j = 0; j < F_IN; j++) acc[j] = fmaf(hk, Ws[k * F_IN + j], acc[j]);
    }
    float4* yp = (float4*)(y2 + (size_t)r * F_IN);
#pragma unroll
    for (int j = 0; j < F_IN / 4; j++)
        yp[j] = make_float4(acc[4 * j], acc[4 * j + 1], acc[4 * j + 2], acc[4 * j + 3]);
}

// ----------------------------------------------------------------
extern "C" void kernel_launch(void* const* d_in, const int* in_sizes, int n_in,
                              void* d_out, int out_size, void* d_ws, size_t ws_size,
                              hipStream_t stream) {
    const float* x  = (const float*)d_in[0];
    const int*   ei = (const int*)d_in[1];
    const float* w  = (const float*)d_in[2];
    // d_in[3] = missing_mask (unused)
    const float* W1 = (const float*)d_in[4];
    const float* b1 = (const float*)d_in[5];
    const float* W2 = (const float*)d_in[6];
    const float* b2 = (const float*)d_in[7];
    float* out = (float*)d_out;

    const int E = in_sizes[1] / 2;
    const int* row = ei;
    const int* col = ei + E;

    // workspace layout
    char* ws = (char*)d_ws;
    size_t off = 0;
    auto alloc = [&](size_t bytes) { void* p = ws + off; off += (bytes + 255) & ~(size_t)255; return p; };
    float* deg    = (float*)alloc(N_NODES * sizeof(float));
    int*   cnt    = (int*)  alloc(N_NODES * sizeof(int));
    int*   cur    = (int*)  alloc(N_NODES * sizeof(int));
    int*   rowptr = (int*)  alloc((N_NODES + 1) * sizeof(int));
    float* nrm    = (float*)alloc(E * sizeof(float));
    int*   src_s  = (int*)  alloc(E * sizeof(int));
    float* nrm_s  = (float*)alloc(E * sizeof(float));
    float* aggx   = (float*)alloc((size_t)T_DIM * N_NODES * F_IN * sizeof(float));  // 15.36 MB
    float* h1     = (float*)alloc((size_t)T_DIM * N_NODES * H_DIM * sizeof(float)); // 30.72 MB
    float* y2     = (float*)alloc((size_t)T_DIM * N_NODES * F_IN * sizeof(float));  // 15.36 MB

    const int rows = T_DIM * N_NODES;
    const int eb = (E + 255) / 256;

    // ---- CSR build
    hipMemsetAsync(deg, 0, N_NODES * sizeof(float), stream);
    hipMemsetAsync(cnt, 0, N_NODES * sizeof(int), stream);
    hipMemsetAsync(cur, 0, N_NODES * sizeof(int), stream);
    deg_hist_kernel<<<eb, 256, 0, stream>>>(col, w, deg, cnt, E);
    norm_kernel<<<eb, 256, 0, stream>>>(row, col, w, deg, nrm, E);
    scan_kernel<<<1, 1024, 0, stream>>>(cnt, rowptr, N_NODES);
    fill_kernel<<<eb, 256, 0, stream>>>(row, col, nrm, rowptr, cur, src_s, nrm_s, E);

    const int nb = (N_NODES + 7) / 8;

    // ---- layer 1: aggregate x (32 feats), then GEMM 32->64 + bias + relu
    gather_agg_kernel<false><<<nb, 256, 0, stream>>>(rowptr, src_s, nrm_s, x, nullptr, aggx, N_NODES);
    gemm1_kernel<<<(rows + 255) / 256, 256, 0, stream>>>(aggx, W1, b1, h1, rows);

    // ---- layer 2: GEMM 64->32, then aggregate + fused tanh(acc + b2)
    gemm2_kernel<<<(rows + 255) / 256, 256, 0, stream>>>(h1, W2, y2, rows);
    gather_agg_kernel<true><<<nb, 256, 0, stream>>>(rowptr, src_s, nrm_s, y2, b2, out, N_NODES);
}

// Round 3
// 234.999 us; speedup vs baseline: 5.2876x; 1.0899x over previous
//
#include <hip/hip_runtime.h>

#define T_DIM   12
#define N_NODES 10000
#define F_IN    32
#define H_DIM   64
#define NCHUNK  (T_DIM / 2)

// ------------------------------------------------ degree (float) + histogram (int), fused
__global__ void deg_hist_kernel(const int* __restrict__ col,
                                const float* __restrict__ w,
                                float* __restrict__ deg,
                                int* __restrict__ cnt, int E) {
    int e = blockIdx.x * blockDim.x + threadIdx.x;
    if (e >= E) return;
    int c = col[e];
    atomicAdd(&deg[c], w[e]);
    atomicAdd(&cnt[c], 1);
}

// ------------------------------------------------ single-block exclusive scan -> rowptr, and seed cur with starts
__global__ __launch_bounds__(1024) void scan_kernel(const int* __restrict__ cnt,
                                                    int* __restrict__ rowptr,
                                                    int* __restrict__ cur, int n) {
    __shared__ int part[1024];
    int tid = threadIdx.x;
    const int per = (n + 1023) / 1024;
    int base = tid * per;
    int s = 0;
    for (int i = 0; i < per; i++) {
        int idx = base + i;
        if (idx < n) s += cnt[idx];
    }
    part[tid] = s;
    __syncthreads();
    for (int off = 1; off < 1024; off <<= 1) {
        int v = 0;
        if (tid >= off) v = part[tid - off];
        __syncthreads();
        if (tid >= off) part[tid] += v;
        __syncthreads();
    }
    int run = (tid == 0) ? 0 : part[tid - 1];
    for (int i = 0; i < per; i++) {
        int idx = base + i;
        if (idx < n) { rowptr[idx] = run; cur[idx] = run; run += cnt[idx]; }
    }
    if (tid == 1023) rowptr[n] = part[1023];
}

// ------------------------------------------------ fill: compute norm inline, bucket-sort edges by dst
__global__ void fill_kernel(const int* __restrict__ row,
                            const int* __restrict__ col,
                            const float* __restrict__ w,
                            const float* __restrict__ deg,
                            int* __restrict__ cur,
                            int2* __restrict__ edge_s, int E) {
    int e = blockIdx.x * blockDim.x + threadIdx.x;
    if (e >= E) return;
    int r = row[e];
    int c = col[e];
    float dr = deg[r];
    float dc = deg[c];
    float ir = dr > 0.f ? 1.0f / sqrtf(fmaxf(dr, 1e-12f)) : 0.f;
    float ic = dc > 0.f ? 1.0f / sqrtf(fmaxf(dc, 1e-12f)) : 0.f;
    float nw = ir * w[e] * ic;
    int pos = atomicAdd(&cur[c], 1);   // cur pre-seeded with rowptr starts -> absolute offset
    edge_s[pos] = make_int2(r, __float_as_int(nw));
}

// ------------------------------------------------ CSR gather-aggregate, t-chunked (2 t per chunk)
// so the source slice (2 x 1.28 MB) stays L2-resident. Optional fused tanh(acc + bias).
template <bool TANH>
__global__ __launch_bounds__(256) void gather_agg_kernel(const int* __restrict__ rowptr,
                                                         const int2* __restrict__ edge_s,
                                                         const float* __restrict__ y,
                                                         const float* __restrict__ bias,
                                                         float* __restrict__ outp, int n) {
    int c = blockIdx.x * 8 + (threadIdx.x >> 5);
    int f = threadIdx.x & 31;
    if (c >= n) return;
    int beg = rowptr[c], end = rowptr[c + 1];
    float b = TANH ? bias[f] : 0.f;
    const float* yf = y + f;
    float* of = outp + (size_t)c * F_IN + f;

    for (int tc = 0; tc < NCHUNK; tc++) {
        const size_t slice = (size_t)N_NODES * F_IN;
        const float* y0 = yf + (size_t)(2 * tc) * slice;
        const float* y1 = y0 + slice;
        float a0 = 0.f, a1 = 0.f;
#pragma unroll 4
        for (int e = beg; e < end; e++) {
            int2 ed = edge_s[e];
            float nw = __int_as_float(ed.y);
            int   so = ed.x * F_IN;
            a0 = fmaf(y0[so], nw, a0);
            a1 = fmaf(y1[so], nw, a1);
        }
        size_t oo = (size_t)(2 * tc) * slice;
        if (TANH) {
            of[oo]         = tanhf(a0 + b);
            of[oo + slice] = tanhf(a1 + b);
        } else {
            of[oo]         = a0;
            of[oo + slice] = a1;
        }
    }
}

// ------------------------------------------------ fused MLP: y2 = relu(aggx @ W1 + b1) @ W2
// Weight indices are wave-uniform -> scalar loads through the constant cache.
__global__ __launch_bounds__(256) void mlp_kernel(const float* __restrict__ aggx,
                                                  const float* __restrict__ W1,
                                                  const float* __restrict__ b1,
                                                  const float* __restrict__ W2,
                                                  float* __restrict__ y2, int rows) {
    int r = blockIdx.x * 256 + threadIdx.x;
    if (r >= rows) return;

    float xv[F_IN];
    const float4* xp = (const float4*)(aggx + (size_t)r * F_IN);
#pragma unroll
    for (int i = 0; i < F_IN / 4; i++) {
        float4 v = xp[i];
        xv[4 * i + 0] = v.x; xv[4 * i + 1] = v.y; xv[4 * i + 2] = v.z; xv[4 * i + 3] = v.w;
    }

    float h[H_DIM];
#pragma unroll
    for (int j = 0; j < H_DIM; j++) h[j] = b1[j];
    for (int k = 0; k < F_IN; k++) {
        float xk = xv[k];
#pragma unroll
        for (int j = 0; j < H_DIM; j++) h[j] = fmaf(xk, W1[k * H_DIM + j], h[j]);
    }
#pragma unroll
    for (int j = 0; j < H_DIM; j++) h[j] = fmaxf(h[j], 0.f);

    float o[F_IN];
#pragma unroll
    for (int j = 0; j < F_IN; j++) o[j] = 0.f;
    for (int k = 0; k < H_DIM; k++) {
        float hk = h[k];
#pragma unroll
        for (int j = 0; j < F_IN; j++) o[j] = fmaf(hk, W2[k * F_IN + j], o[j]);
    }

    float4* yp = (float4*)(y2 + (size_t)r * F_IN);
#pragma unroll
    for (int j = 0; j < F_IN / 4; j++)
        yp[j] = make_float4(o[4 * j], o[4 * j + 1], o[4 * j + 2], o[4 * j + 3]);
}

// ----------------------------------------------------------------
extern "C" void kernel_launch(void* const* d_in, const int* in_sizes, int n_in,
                              void* d_out, int out_size, void* d_ws, size_t ws_size,
                              hipStream_t stream) {
    const float* x  = (const float*)d_in[0];
    const int*   ei = (const int*)d_in[1];
    const float* w  = (const float*)d_in[2];
    // d_in[3] = missing_mask (unused)
    const float* W1 = (const float*)d_in[4];
    const float* b1 = (const float*)d_in[5];
    const float* W2 = (const float*)d_in[6];
    const float* b2 = (const float*)d_in[7];
    float* out = (float*)d_out;

    const int E = in_sizes[1] / 2;
    const int* row = ei;
    const int* col = ei + E;

    char* ws = (char*)d_ws;
    size_t off = 0;
    auto alloc = [&](size_t bytes) { void* p = ws + off; off += (bytes + 255) & ~(size_t)255; return p; };
    float* deg    = (float*)alloc(N_NODES * sizeof(float));
    int*   cnt    = (int*)  alloc(N_NODES * sizeof(int));
    int*   cur    = (int*)  alloc(N_NODES * sizeof(int));
    int*   rowptr = (int*)  alloc((N_NODES + 1) * sizeof(int));
    int2*  edge_s = (int2*) alloc((size_t)E * sizeof(int2));
    float* aggx   = (float*)alloc((size_t)T_DIM * N_NODES * F_IN * sizeof(float));  // 15.36 MB
    float* y2     = (float*)alloc((size_t)T_DIM * N_NODES * F_IN * sizeof(float));  // 15.36 MB

    const int rows = T_DIM * N_NODES;
    const int eb = (E + 255) / 256;
    const int nb = (N_NODES + 7) / 8;

    // ---- CSR build
    hipMemsetAsync(deg, 0, N_NODES * sizeof(float), stream);
    hipMemsetAsync(cnt, 0, N_NODES * sizeof(int), stream);
    deg_hist_kernel<<<eb, 256, 0, stream>>>(col, w, deg, cnt, E);
    scan_kernel<<<1, 1024, 0, stream>>>(cnt, rowptr, cur, N_NODES);
    fill_kernel<<<eb, 256, 0, stream>>>(row, col, w, deg, cur, edge_s, E);

    // ---- layer 1: aggregate x (L2-chunked), then fused MLP (32->64 relu 64->32)
    gather_agg_kernel<false><<<nb, 256, 0, stream>>>(rowptr, edge_s, x, nullptr, aggx, N_NODES);
    mlp_kernel<<<(rows + 255) / 256, 256, 0, stream>>>(aggx, W1, b1, W2, y2, rows);

    // ---- layer 2: aggregate y2 (L2-chunked) with fused tanh(acc + b2)
    gather_agg_kernel<true><<<nb, 256, 0, stream>>>(rowptr, edge_s, y2, b2, out, N_NODES);
}

// Round 4
// 233.282 us; speedup vs baseline: 5.3265x; 1.0074x over previous
//
#include <hip/hip_runtime.h>

#define T_DIM   12
#define N_NODES 10000
#define F_IN    32
#define H_DIM   64

// ------------------------------------------------ degree (float) + histogram (int), fused
__global__ void deg_hist_kernel(const int* __restrict__ col,
                                const float* __restrict__ w,
                                float* __restrict__ deg,
                                int* __restrict__ cnt, int E) {
    int e = blockIdx.x * blockDim.x + threadIdx.x;
    if (e >= E) return;
    int c = col[e];
    atomicAdd(&deg[c], w[e]);
    atomicAdd(&cnt[c], 1);
}

// ------------------------------------------------ single-block exclusive scan -> rowptr, seed cur
__global__ __launch_bounds__(1024) void scan_kernel(const int* __restrict__ cnt,
                                                    int* __restrict__ rowptr,
                                                    int* __restrict__ cur, int n) {
    __shared__ int part[1024];
    int tid = threadIdx.x;
    const int per = (n + 1023) / 1024;
    int base = tid * per;
    int s = 0;
    for (int i = 0; i < per; i++) {
        int idx = base + i;
        if (idx < n) s += cnt[idx];
    }
    part[tid] = s;
    __syncthreads();
    for (int off = 1; off < 1024; off <<= 1) {
        int v = 0;
        if (tid >= off) v = part[tid - off];
        __syncthreads();
        if (tid >= off) part[tid] += v;
        __syncthreads();
    }
    int run = (tid == 0) ? 0 : part[tid - 1];
    for (int i = 0; i < per; i++) {
        int idx = base + i;
        if (idx < n) { rowptr[idx] = run; cur[idx] = run; run += cnt[idx]; }
    }
    if (tid == 1023) rowptr[n] = part[1023];
}

// ------------------------------------------------ fill: norm inline, bucket-sort edges by dst
__global__ void fill_kernel(const int* __restrict__ row,
                            const int* __restrict__ col,
                            const float* __restrict__ w,
                            const float* __restrict__ deg,
                            int* __restrict__ cur,
                            int2* __restrict__ edge_s, int E) {
    int e = blockIdx.x * blockDim.x + threadIdx.x;
    if (e >= E) return;
    int r = row[e];
    int c = col[e];
    float dr = deg[r];
    float dc = deg[c];
    float ir = dr > 0.f ? 1.0f / sqrtf(fmaxf(dr, 1e-12f)) : 0.f;
    float ic = dc > 0.f ? 1.0f / sqrtf(fmaxf(dc, 1e-12f)) : 0.f;
    float nw = ir * w[e] * ic;
    int pos = atomicAdd(&cur[c], 1);   // cur pre-seeded with rowptr starts -> absolute offset
    edge_s[pos] = make_int2(r, __float_as_int(nw));
}

// ------------------------------------------------ CSR gather-aggregate, single pass over edges.
// 32 lanes per dst node: lane = 8 feature-quads (float4) x 4 t-slices; 3 loads/edge cover t=tl+4i.
// Per wave: 2 nodes. Optional fused tanh(acc + bias) epilogue.
template <bool TANH>
__global__ __launch_bounds__(256) void gather_agg_kernel(const int* __restrict__ rowptr,
                                                         const int2* __restrict__ edge_s,
                                                         const float* __restrict__ y,
                                                         const float* __restrict__ bias,
                                                         float* __restrict__ outp, int n) {
    int c = blockIdx.x * 8 + (threadIdx.x >> 5);   // node per 32-lane group
    if (c >= n) return;
    int l  = threadIdx.x & 31;
    int fq = l & 7;        // feature quad: features 4*fq .. 4*fq+3
    int tl = l >> 3;       // t-slice base: t = tl + 4*i, i = 0..2

    int beg = rowptr[c], end = rowptr[c + 1];
    const size_t slice = (size_t)N_NODES * F_IN;
    const float* ybase = y + (size_t)tl * slice + 4 * fq;

    float4 a0 = {0.f, 0.f, 0.f, 0.f};
    float4 a1 = {0.f, 0.f, 0.f, 0.f};
    float4 a2 = {0.f, 0.f, 0.f, 0.f};

#pragma unroll 2
    for (int e = beg; e < end; e++) {
        int2 ed = edge_s[e];
        float nw = __int_as_float(ed.y);
        const float* p = ybase + (size_t)ed.x * F_IN;
        float4 v0 = *(const float4*)(p);
        float4 v1 = *(const float4*)(p + 4 * slice);
        float4 v2 = *(const float4*)(p + 8 * slice);
        a0.x = fmaf(v0.x, nw, a0.x); a0.y = fmaf(v0.y, nw, a0.y);
        a0.z = fmaf(v0.z, nw, a0.z); a0.w = fmaf(v0.w, nw, a0.w);
        a1.x = fmaf(v1.x, nw, a1.x); a1.y = fmaf(v1.y, nw, a1.y);
        a1.z = fmaf(v1.z, nw, a1.z); a1.w = fmaf(v1.w, nw, a1.w);
        a2.x = fmaf(v2.x, nw, a2.x); a2.y = fmaf(v2.y, nw, a2.y);
        a2.z = fmaf(v2.z, nw, a2.z); a2.w = fmaf(v2.w, nw, a2.w);
    }

    float* ob = outp + (size_t)tl * slice + (size_t)c * F_IN + 4 * fq;
    if (TANH) {
        float4 b = *(const float4*)(bias + 4 * fq);
        a0.x = tanhf(a0.x + b.x); a0.y = tanhf(a0.y + b.y);
        a0.z = tanhf(a0.z + b.z); a0.w = tanhf(a0.w + b.w);
        a1.x = tanhf(a1.x + b.x); a1.y = tanhf(a1.y + b.y);
        a1.z = tanhf(a1.z + b.z); a1.w = tanhf(a1.w + b.w);
        a2.x = tanhf(a2.x + b.x); a2.y = tanhf(a2.y + b.y);
        a2.z = tanhf(a2.z + b.z); a2.w = tanhf(a2.w + b.w);
    }
    *(float4*)(ob)             = a0;
    *(float4*)(ob + 4 * slice) = a1;
    *(float4*)(ob + 8 * slice) = a2;
}

// ------------------------------------------------ fused MLP: y2 = relu(aggx @ W1 + b1) @ W2
__global__ __launch_bounds__(256) void mlp_kernel(const float* __restrict__ aggx,
                                                  const float* __restrict__ W1,
                                                  const float* __restrict__ b1,
                                                  const float* __restrict__ W2,
                                                  float* __restrict__ y2, int rows) {
    int r = blockIdx.x * 256 + threadIdx.x;
    if (r >= rows) return;

    float xv[F_IN];
    const float4* xp = (const float4*)(aggx + (size_t)r * F_IN);
#pragma unroll
    for (int i = 0; i < F_IN / 4; i++) {
        float4 v = xp[i];
        xv[4 * i + 0] = v.x; xv[4 * i + 1] = v.y; xv[4 * i + 2] = v.z; xv[4 * i + 3] = v.w;
    }

    float h[H_DIM];
#pragma unroll
    for (int j = 0; j < H_DIM; j++) h[j] = b1[j];
    for (int k = 0; k < F_IN; k++) {
        float xk = xv[k];
#pragma unroll
        for (int j = 0; j < H_DIM; j++) h[j] = fmaf(xk, W1[k * H_DIM + j], h[j]);
    }
#pragma unroll
    for (int j = 0; j < H_DIM; j++) h[j] = fmaxf(h[j], 0.f);

    float o[F_IN];
#pragma unroll
    for (int j = 0; j < F_IN; j++) o[j] = 0.f;
    for (int k = 0; k < H_DIM; k++) {
        float hk = h[k];
#pragma unroll
        for (int j = 0; j < F_IN; j++) o[j] = fmaf(hk, W2[k * F_IN + j], o[j]);
    }

    float4* yp = (float4*)(y2 + (size_t)r * F_IN);
#pragma unroll
    for (int j = 0; j < F_IN / 4; j++)
        yp[j] = make_float4(o[4 * j], o[4 * j + 1], o[4 * j + 2], o[4 * j + 3]);
}

// ----------------------------------------------------------------
extern "C" void kernel_launch(void* const* d_in, const int* in_sizes, int n_in,
                              void* d_out, int out_size, void* d_ws, size_t ws_size,
                              hipStream_t stream) {
    const float* x  = (const float*)d_in[0];
    const int*   ei = (const int*)d_in[1];
    const float* w  = (const float*)d_in[2];
    // d_in[3] = missing_mask (unused)
    const float* W1 = (const float*)d_in[4];
    const float* b1 = (const float*)d_in[5];
    const float* W2 = (const float*)d_in[6];
    const float* b2 = (const float*)d_in[7];
    float* out = (float*)d_out;

    const int E = in_sizes[1] / 2;
    const int* row = ei;
    const int* col = ei + E;

    char* ws = (char*)d_ws;
    size_t off = 0;
    auto alloc = [&](size_t bytes) { void* p = ws + off; off += (bytes + 255) & ~(size_t)255; return p; };
    float* deg    = (float*)alloc(N_NODES * sizeof(float));          // [0, 40000) pad->40192
    int*   cnt    = (int*)  alloc(N_NODES * sizeof(int));            // [40192, 80192)
    int*   cur    = (int*)  alloc(N_NODES * sizeof(int));
    int*   rowptr = (int*)  alloc((N_NODES + 1) * sizeof(int));
    int2*  edge_s = (int2*) alloc((size_t)E * sizeof(int2));
    float* aggx   = (float*)alloc((size_t)T_DIM * N_NODES * F_IN * sizeof(float));  // 15.36 MB
    float* y2     = (float*)alloc((size_t)T_DIM * N_NODES * F_IN * sizeof(float));  // 15.36 MB

    const int rows = T_DIM * N_NODES;
    const int eb = (E + 255) / 256;
    const int nb = (N_NODES + 7) / 8;

    // ---- CSR build (single memset covers contiguous deg+cnt)
    hipMemsetAsync(deg, 0, (char*)(cnt + N_NODES) - (char*)deg, stream);
    deg_hist_kernel<<<eb, 256, 0, stream>>>(col, w, deg, cnt, E);
    scan_kernel<<<1, 1024, 0, stream>>>(cnt, rowptr, cur, N_NODES);
    fill_kernel<<<eb, 256, 0, stream>>>(row, col, w, deg, cur, edge_s, E);

    // ---- layer 1: aggregate x (all 12 t, float4 lanes), then fused MLP (32->64 relu 64->32)
    gather_agg_kernel<false><<<nb, 256, 0, stream>>>(rowptr, edge_s, x, nullptr, aggx, N_NODES);
    mlp_kernel<<<(rows + 255) / 256, 256, 0, stream>>>(aggx, W1, b1, W2, y2, rows);

    // ---- layer 2: aggregate y2 with fused tanh(acc + b2)
    gather_agg_kernel<true><<<nb, 256, 0, stream>>>(rowptr, edge_s, y2, b2, out, N_NODES);
}

// Round 5
// 186.314 us; speedup vs baseline: 6.6693x; 1.2521x over previous
//
#include <hip/hip_runtime.h>
#include <hip/hip_fp16.h>

#define T_DIM   12
#define N_NODES 10000
#define F_IN    32
#define H_DIM   64
#define NCH     3            // t-chunks
#define TC      4            // timesteps per chunk
#define CHROW   (TC * F_IN)  // fp16 elements per node per chunk = 128 (256 B)

// ------------------------------------------------ fused: degree+histogram (blocks [0,eb)) and
// x fp32 [t][n][f] -> xh fp16 [ch][n][tc][f] convert (blocks [eb, eb+cb))
__global__ void deg_hist_conv_kernel(const int* __restrict__ col,
                                     const float* __restrict__ w,
                                     float* __restrict__ deg,
                                     int* __restrict__ cnt, int E, int eb,
                                     const float* __restrict__ x,
                                     __half* __restrict__ xh) {
    int b = blockIdx.x;
    if (b < eb) {
        int e = b * 256 + threadIdx.x;
        if (e >= E) return;
        int c = col[e];
        atomicAdd(&deg[c], w[e]);
        atomicAdd(&cnt[c], 1);
    } else {
        int r = (b - eb) * 256 + threadIdx.x;   // r = t*N + n
        if (r >= T_DIM * N_NODES) return;
        int t = r / N_NODES;
        int n = r - t * N_NODES;
        const float4* xp = (const float4*)(x + (size_t)r * F_IN);
        union { uint32_t u[16]; uint4 q[4]; } pk;
#pragma unroll
        for (int i = 0; i < 8; i++) {
            float4 v = xp[i];
            __half2 h0 = __floats2half2_rn(v.x, v.y);
            __half2 h1 = __floats2half2_rn(v.z, v.w);
            pk.u[2 * i]     = *(uint32_t*)&h0;
            pk.u[2 * i + 1] = *(uint32_t*)&h1;
        }
        // dst: ((t>>2)*N + n)*CHROW + (t&3)*F_IN   (fp16 units), 64 B per thread
        uint4* dp = (uint4*)(xh + ((size_t)(t >> 2) * N_NODES + n) * CHROW + (size_t)(t & 3) * F_IN);
#pragma unroll
        for (int i = 0; i < 4; i++) dp[i] = pk.q[i];
    }
}

// ------------------------------------------------ single-block exclusive scan -> rowptr, seed cur
__global__ __launch_bounds__(1024) void scan_kernel(const int* __restrict__ cnt,
                                                    int* __restrict__ rowptr,
                                                    int* __restrict__ cur, int n) {
    __shared__ int part[1024];
    int tid = threadIdx.x;
    const int per = (n + 1023) / 1024;
    int base = tid * per;
    int s = 0;
    for (int i = 0; i < per; i++) {
        int idx = base + i;
        if (idx < n) s += cnt[idx];
    }
    part[tid] = s;
    __syncthreads();
    for (int off = 1; off < 1024; off <<= 1) {
        int v = 0;
        if (tid >= off) v = part[tid - off];
        __syncthreads();
        if (tid >= off) part[tid] += v;
        __syncthreads();
    }
    int run = (tid == 0) ? 0 : part[tid - 1];
    for (int i = 0; i < per; i++) {
        int idx = base + i;
        if (idx < n) { rowptr[idx] = run; cur[idx] = run; run += cnt[idx]; }
    }
    if (tid == 1023) rowptr[n] = part[1023];
}

// ------------------------------------------------ fill: norm inline, bucket-sort edges by dst
__global__ void fill_kernel(const int* __restrict__ row,
                            const int* __restrict__ col,
                            const float* __restrict__ w,
                            const float* __restrict__ deg,
                            int* __restrict__ cur,
                            int2* __restrict__ edge_s, int E) {
    int e = blockIdx.x * blockDim.x + threadIdx.x;
    if (e >= E) return;
    int r = row[e];
    int c = col[e];
    float dr = deg[r];
    float dc = deg[c];
    float ir = dr > 0.f ? 1.0f / sqrtf(fmaxf(dr, 1e-12f)) : 0.f;
    float ic = dc > 0.f ? 1.0f / sqrtf(fmaxf(dc, 1e-12f)) : 0.f;
    float nw = ir * w[e] * ic;
    int pos = atomicAdd(&cur[c], 1);   // cur pre-seeded with rowptr starts
    edge_s[pos] = make_int2(r, __float_as_int(nw));
}

// ------------------------------------------------ CSR gather-aggregate from fp16 node-major
// chunked source yh[ch][n][4t][f]. 32 lanes per dst node; per edge per chunk ONE dwordx2/lane
// (256 B contiguous node row, L2-resident chunk). fp32 accumulate; optional fused tanh+bias.
template <bool TANH>
__global__ __launch_bounds__(256) void gather_agg_kernel(const int* __restrict__ rowptr,
                                                         const int2* __restrict__ edge_s,
                                                         const __half* __restrict__ yh,
                                                         const float* __restrict__ bias,
                                                         float* __restrict__ outp, int n) {
    int c = blockIdx.x * 8 + (threadIdx.x >> 5);
    if (c >= n) return;
    int l = threadIdx.x & 31;           // lane: tc = l>>3, f-quad = l&7 -> fp16 offset 4*l

    int beg = rowptr[c], end = rowptr[c + 1];
    float4 b4 = {0.f, 0.f, 0.f, 0.f};
    if (TANH) b4 = *(const float4*)(bias + 4 * (l & 7));

#pragma unroll
    for (int ch = 0; ch < NCH; ch++) {
        const __half* base = yh + (size_t)ch * N_NODES * CHROW + 4 * l;
        float4 a = {0.f, 0.f, 0.f, 0.f};
#pragma unroll 8
        for (int e = beg; e < end; e++) {
            int2 ed = edge_s[e];
            float nw = __int_as_float(ed.y);
            uint2 u = *(const uint2*)(base + (size_t)ed.x * CHROW);
            __half2 h0 = *(__half2*)&u.x;
            __half2 h1 = *(__half2*)&u.y;
            float2 f0 = __half22float2(h0);
            float2 f1 = __half22float2(h1);
            a.x = fmaf(f0.x, nw, a.x);
            a.y = fmaf(f0.y, nw, a.y);
            a.z = fmaf(f1.x, nw, a.z);
            a.w = fmaf(f1.y, nw, a.w);
        }
        int t = ch * TC + (l >> 3);
        float* op = outp + ((size_t)t * N_NODES + c) * F_IN + 4 * (l & 7);
        if (TANH) {
            a.x = tanhf(a.x + b4.x); a.y = tanhf(a.y + b4.y);
            a.z = tanhf(a.z + b4.z); a.w = tanhf(a.w + b4.w);
        }
        *(float4*)op = a;
    }
}

// ------------------------------------------------ fused MLP: y2 = relu(aggx @ W1 + b1) @ W2,
// emitted as fp16 node-major chunked y2h[ch][n][4t][f]
__global__ __launch_bounds__(256) void mlp_kernel(const float* __restrict__ aggx,
                                                  const float* __restrict__ W1,
                                                  const float* __restrict__ b1,
                                                  const float* __restrict__ W2,
                                                  __half* __restrict__ y2h, int rows) {
    int r = blockIdx.x * 256 + threadIdx.x;   // r = t*N + n
    if (r >= rows) return;

    float xv[F_IN];
    const float4* xp = (const float4*)(aggx + (size_t)r * F_IN);
#pragma unroll
    for (int i = 0; i < F_IN / 4; i++) {
        float4 v = xp[i];
        xv[4 * i + 0] = v.x; xv[4 * i + 1] = v.y; xv[4 * i + 2] = v.z; xv[4 * i + 3] = v.w;
    }

    float h[H_DIM];
#pragma unroll
    for (int j = 0; j < H_DIM; j++) h[j] = b1[j];
    for (int k = 0; k < F_IN; k++) {
        float xk = xv[k];
#pragma unroll
        for (int j = 0; j < H_DIM; j++) h[j] = fmaf(xk, W1[k * H_DIM + j], h[j]);
    }
#pragma unroll
    for (int j = 0; j < H_DIM; j++) h[j] = fmaxf(h[j], 0.f);

    float o[F_IN];
#pragma unroll
    for (int j = 0; j < F_IN; j++) o[j] = 0.f;
    for (int k = 0; k < H_DIM; k++) {
        float hk = h[k];
#pragma unroll
        for (int j = 0; j < F_IN; j++) o[j] = fmaf(hk, W2[k * F_IN + j], o[j]);
    }

    union { uint32_t u[16]; uint4 q[4]; } pk;
#pragma unroll
    for (int i = 0; i < 16; i++) {
        __half2 hh = __floats2half2_rn(o[2 * i], o[2 * i + 1]);
        pk.u[i] = *(uint32_t*)&hh;
    }
    int t = r / N_NODES;
    int n = r - t * N_NODES;
    uint4* dp = (uint4*)(y2h + ((size_t)(t >> 2) * N_NODES + n) * CHROW + (size_t)(t & 3) * F_IN);
#pragma unroll
    for (int i = 0; i < 4; i++) dp[i] = pk.q[i];
}

// ----------------------------------------------------------------
extern "C" void kernel_launch(void* const* d_in, const int* in_sizes, int n_in,
                              void* d_out, int out_size, void* d_ws, size_t ws_size,
                              hipStream_t stream) {
    const float* x  = (const float*)d_in[0];
    const int*   ei = (const int*)d_in[1];
    const float* w  = (const float*)d_in[2];
    // d_in[3] = missing_mask (unused)
    const float* W1 = (const float*)d_in[4];
    const float* b1 = (const float*)d_in[5];
    const float* W2 = (const float*)d_in[6];
    const float* b2 = (const float*)d_in[7];
    float* out = (float*)d_out;

    const int E = in_sizes[1] / 2;
    const int* row = ei;
    const int* col = ei + E;

    char* ws = (char*)d_ws;
    size_t off = 0;
    auto alloc = [&](size_t bytes) { void* p = ws + off; off += (bytes + 255) & ~(size_t)255; return p; };
    float*  deg    = (float*) alloc(N_NODES * sizeof(float));
    int*    cnt    = (int*)   alloc(N_NODES * sizeof(int));
    int*    cur    = (int*)   alloc(N_NODES * sizeof(int));
    int*    rowptr = (int*)   alloc((N_NODES + 1) * sizeof(int));
    int2*   edge_s = (int2*)  alloc((size_t)E * sizeof(int2));                         // 2.56 MB
    __half* xh     = (__half*)alloc((size_t)NCH * N_NODES * CHROW * sizeof(__half));   // 7.68 MB
    __half* y2h    = (__half*)alloc((size_t)NCH * N_NODES * CHROW * sizeof(__half));   // 7.68 MB
    float*  aggx   = (float*) alloc((size_t)T_DIM * N_NODES * F_IN * sizeof(float));   // 15.36 MB

    const int rows = T_DIM * N_NODES;
    const int eb = (E + 255) / 256;
    const int cb = (rows + 255) / 256;
    const int nb = (N_NODES + 7) / 8;

    // ---- CSR build + fp16 convert (fused extra blocks)
    hipMemsetAsync(deg, 0, (char*)(cnt + N_NODES) - (char*)deg, stream);
    deg_hist_conv_kernel<<<eb + cb, 256, 0, stream>>>(col, w, deg, cnt, E, eb, x, xh);
    scan_kernel<<<1, 1024, 0, stream>>>(cnt, rowptr, cur, N_NODES);
    fill_kernel<<<eb, 256, 0, stream>>>(row, col, w, deg, cur, edge_s, E);

    // ---- layer 1: aggregate xh (fp16, chunk-resident), fused MLP 32->64 relu 64->32 -> y2h fp16
    gather_agg_kernel<false><<<nb, 256, 0, stream>>>(rowptr, edge_s, xh, nullptr, aggx, N_NODES);
    mlp_kernel<<<cb, 256, 0, stream>>>(aggx, W1, b1, W2, y2h, rows);

    // ---- layer 2: aggregate y2h with fused tanh(acc + b2) -> out fp32 [t][n][f]
    gather_agg_kernel<true><<<nb, 256, 0, stream>>>(rowptr, edge_s, y2h, b2, out, N_NODES);
}

// Round 6
// 176.561 us; speedup vs baseline: 7.0377x; 1.0552x over previous
//
#include <hip/hip_runtime.h>
#include <hip/hip_fp16.h>

#define T_DIM   12
#define N_NODES 10000
#define F_IN    32
#define H_DIM   64
#define NCH     3            // t-chunks
#define TC      4            // timesteps per chunk
#define CHROW   (TC * F_IN)  // elements per node per chunk = 128
#define NGRP    (N_NODES / 16)        // 625 node-groups of 16
#define NTASK   (NCH * NGRP)          // 1875 wave tasks

// ------------------------------------------------ fused: degree+histogram (blocks [0,eb)) and
// x fp32 [t][n][f] -> xh fp16 chunked [ch][n][tc][f] (blocks [eb, eb+cb)), wave-aligned mapping
__global__ void deg_hist_conv_kernel(const int* __restrict__ col,
                                     const float* __restrict__ w,
                                     float* __restrict__ deg,
                                     int* __restrict__ cnt, int E, int eb,
                                     const float* __restrict__ x,
                                     __half* __restrict__ xh) {
    int b = blockIdx.x;
    if (b < eb) {
        int e = b * 256 + threadIdx.x;
        if (e >= E) return;
        int c = col[e];
        atomicAdd(&deg[c], w[e]);
        atomicAdd(&cnt[c], 1);
    } else {
        int task = (b - eb) * 4 + (threadIdx.x >> 6);
        if (task >= NTASK) return;
        int l  = threadIdx.x & 63;
        int ch = task / NGRP;
        int ng = task - ch * NGRP;
        int n  = ng * 16 + (l >> 2);
        int t  = ch * TC + (l & 3);
        const float4* xp = (const float4*)(x + ((size_t)t * N_NODES + n) * F_IN);
        union { uint32_t u[16]; uint4 q[4]; } pk;
#pragma unroll
        for (int i = 0; i < 8; i++) {
            float4 v = xp[i];
            __half2 h0 = __floats2half2_rn(v.x, v.y);
            __half2 h1 = __floats2half2_rn(v.z, v.w);
            pk.u[2 * i]     = *(uint32_t*)&h0;
            pk.u[2 * i + 1] = *(uint32_t*)&h1;
        }
        // chunk-linear row = ch*N*TC + ng*64 + l  -> wave writes contiguous 4 KB
        uint4* dp = (uint4*)(xh + ((size_t)ch * N_NODES * TC + ng * 64 + l) * F_IN);
#pragma unroll
        for (int i = 0; i < 4; i++) dp[i] = pk.q[i];
    }
}

// ------------------------------------------------ single-block exclusive scan -> rowptr, seed cur
__global__ __launch_bounds__(1024) void scan_kernel(const int* __restrict__ cnt,
                                                    int* __restrict__ rowptr,
                                                    int* __restrict__ cur, int n) {
    __shared__ int part[1024];
    int tid = threadIdx.x;
    const int per = (n + 1023) / 1024;
    int base = tid * per;
    int s = 0;
    for (int i = 0; i < per; i++) {
        int idx = base + i;
        if (idx < n) s += cnt[idx];
    }
    part[tid] = s;
    __syncthreads();
    for (int off = 1; off < 1024; off <<= 1) {
        int v = 0;
        if (tid >= off) v = part[tid - off];
        __syncthreads();
        if (tid >= off) part[tid] += v;
        __syncthreads();
    }
    int run = (tid == 0) ? 0 : part[tid - 1];
    for (int i = 0; i < per; i++) {
        int idx = base + i;
        if (idx < n) { rowptr[idx] = run; cur[idx] = run; run += cnt[idx]; }
    }
    if (tid == 1023) rowptr[n] = part[1023];
}

// ------------------------------------------------ fill: norm inline, bucket-sort edges by dst
__global__ void fill_kernel(const int* __restrict__ row,
                            const int* __restrict__ col,
                            const float* __restrict__ w,
                            const float* __restrict__ deg,
                            int* __restrict__ cur,
                            int2* __restrict__ edge_s, int E) {
    int e = blockIdx.x * blockDim.x + threadIdx.x;
    if (e >= E) return;
    int r = row[e];
    int c = col[e];
    float dr = deg[r];
    float dc = deg[c];
    float ir = dr > 0.f ? 1.0f / sqrtf(fmaxf(dr, 1e-12f)) : 0.f;
    float ic = dc > 0.f ? 1.0f / sqrtf(fmaxf(dc, 1e-12f)) : 0.f;
    float nw = ir * w[e] * ic;
    int pos = atomicAdd(&cur[c], 1);   // cur pre-seeded with rowptr starts
    edge_s[pos] = make_int2(r, __float_as_int(nw));
}

// ------------------------------------------------ CSR gather-aggregate from fp16 chunked source.
// 32 lanes per dst node; per edge per chunk ONE dwordx2/lane (256 B contiguous node row).
// TANH=false: write fp32 chunked [ch][n][tc][f] (contiguous 512 B/node).
// TANH=true : write fp32 standard [t][n][f] with fused tanh(acc+bias).
template <bool TANH>
__global__ __launch_bounds__(256) void gather_agg_kernel(const int* __restrict__ rowptr,
                                                         const int2* __restrict__ edge_s,
                                                         const __half* __restrict__ yh,
                                                         const float* __restrict__ bias,
                                                         float* __restrict__ outp, int n) {
    int c = blockIdx.x * 8 + (threadIdx.x >> 5);
    if (c >= n) return;
    int l = threadIdx.x & 31;           // lane: tc = l>>3, f-quad = l&7 -> fp16 offset 4*l

    int beg = rowptr[c], end = rowptr[c + 1];
    float4 b4 = {0.f, 0.f, 0.f, 0.f};
    if (TANH) b4 = *(const float4*)(bias + 4 * (l & 7));

#pragma unroll
    for (int ch = 0; ch < NCH; ch++) {
        const __half* base = yh + (size_t)ch * N_NODES * CHROW + 4 * l;
        float4 a = {0.f, 0.f, 0.f, 0.f};
#pragma unroll 8
        for (int e = beg; e < end; e++) {
            int2 ed = edge_s[e];
            float nw = __int_as_float(ed.y);
            uint2 u = *(const uint2*)(base + (size_t)ed.x * CHROW);
            __half2 h0 = *(__half2*)&u.x;
            __half2 h1 = *(__half2*)&u.y;
            float2 f0 = __half22float2(h0);
            float2 f1 = __half22float2(h1);
            a.x = fmaf(f0.x, nw, a.x);
            a.y = fmaf(f0.y, nw, a.y);
            a.z = fmaf(f1.x, nw, a.z);
            a.w = fmaf(f1.y, nw, a.w);
        }
        if (TANH) {
            a.x = tanhf(a.x + b4.x); a.y = tanhf(a.y + b4.y);
            a.z = tanhf(a.z + b4.z); a.w = tanhf(a.w + b4.w);
            float* op = outp + ((size_t)(ch * TC + (l >> 3)) * N_NODES + c) * F_IN + 4 * (l & 7);
            *(float4*)op = a;
        } else {
            // chunked fp32: group writes contiguous 512 B per node
            float* op = outp + ((size_t)ch * N_NODES + c) * CHROW + 4 * l;
            *(float4*)op = a;
        }
    }
}

// ------------------------------------------------ fused MLP: y2 = relu(aggx @ W1 + b1) @ W2.
// aggx and y2h both in chunked node-major layout; wave-aligned rows -> fully coalesced I/O.
__global__ __launch_bounds__(256) void mlp_kernel(const float* __restrict__ aggx,
                                                  const float* __restrict__ W1g,
                                                  const float* __restrict__ b1,
                                                  const float* __restrict__ W2g,
                                                  __half* __restrict__ y2h) {
    __shared__ float W1s[F_IN * H_DIM];
    __shared__ float W2s[H_DIM * F_IN];
    __shared__ float b1s[H_DIM];
    for (int i = threadIdx.x; i < F_IN * H_DIM; i += 256) {
        W1s[i] = W1g[i];
        W2s[i] = W2g[i];
    }
    if (threadIdx.x < H_DIM) b1s[threadIdx.x] = b1[threadIdx.x];
    __syncthreads();

    int task = blockIdx.x * 4 + (threadIdx.x >> 6);
    if (task >= NTASK) return;
    int l  = threadIdx.x & 63;
    int ch = task / NGRP;
    int ng = task - ch * NGRP;
    size_t rowbase = (size_t)ch * N_NODES * TC + ng * 64 + l;   // chunk-linear (n,tc) row

    float xv[F_IN];
    const float4* xp = (const float4*)(aggx + rowbase * F_IN);
#pragma unroll
    for (int i = 0; i < F_IN / 4; i++) {
        float4 v = xp[i];
        xv[4 * i + 0] = v.x; xv[4 * i + 1] = v.y; xv[4 * i + 2] = v.z; xv[4 * i + 3] = v.w;
    }

    float h[H_DIM];
#pragma unroll
    for (int j = 0; j < H_DIM; j++) h[j] = b1s[j];
    for (int k = 0; k < F_IN; k++) {
        float xk = xv[k];
#pragma unroll
        for (int j = 0; j < H_DIM; j++) h[j] = fmaf(xk, W1s[k * H_DIM + j], h[j]);
    }
#pragma unroll
    for (int j = 0; j < H_DIM; j++) h[j] = fmaxf(h[j], 0.f);

    float o[F_IN];
#pragma unroll
    for (int j = 0; j < F_IN; j++) o[j] = 0.f;
    for (int k = 0; k < H_DIM; k++) {
        float hk = h[k];
#pragma unroll
        for (int j = 0; j < F_IN; j++) o[j] = fmaf(hk, W2s[k * F_IN + j], o[j]);
    }

    union { uint32_t u[16]; uint4 q[4]; } pk;
#pragma unroll
    for (int i = 0; i < 16; i++) {
        __half2 hh = __floats2half2_rn(o[2 * i], o[2 * i + 1]);
        pk.u[i] = *(uint32_t*)&hh;
    }
    uint4* dp = (uint4*)(y2h + rowbase * F_IN);
#pragma unroll
    for (int i = 0; i < 4; i++) dp[i] = pk.q[i];
}

// ----------------------------------------------------------------
extern "C" void kernel_launch(void* const* d_in, const int* in_sizes, int n_in,
                              void* d_out, int out_size, void* d_ws, size_t ws_size,
                              hipStream_t stream) {
    const float* x  = (const float*)d_in[0];
    const int*   ei = (const int*)d_in[1];
    const float* w  = (const float*)d_in[2];
    // d_in[3] = missing_mask (unused)
    const float* W1 = (const float*)d_in[4];
    const float* b1 = (const float*)d_in[5];
    const float* W2 = (const float*)d_in[6];
    const float* b2 = (const float*)d_in[7];
    float* out = (float*)d_out;

    const int E = in_sizes[1] / 2;
    const int* row = ei;
    const int* col = ei + E;

    char* ws = (char*)d_ws;
    size_t off = 0;
    auto alloc = [&](size_t bytes) { void* p = ws + off; off += (bytes + 255) & ~(size_t)255; return p; };
    float*  deg    = (float*) alloc(N_NODES * sizeof(float));
    int*    cnt    = (int*)   alloc(N_NODES * sizeof(int));
    int*    cur    = (int*)   alloc(N_NODES * sizeof(int));
    int*    rowptr = (int*)   alloc((N_NODES + 1) * sizeof(int));
    int2*   edge_s = (int2*)  alloc((size_t)E * sizeof(int2));                          // 2.56 MB
    __half* xh     = (__half*)alloc((size_t)NCH * N_NODES * CHROW * sizeof(__half));    // 7.68 MB
    __half* y2h    = (__half*)alloc((size_t)NCH * N_NODES * CHROW * sizeof(__half));    // 7.68 MB
    float*  aggx   = (float*) alloc((size_t)NCH * N_NODES * CHROW * sizeof(float));     // 15.36 MB

    const int eb = (E + 255) / 256;
    const int cb = (NTASK + 3) / 4;          // 469 blocks, 4 wave-tasks each
    const int nb = (N_NODES + 7) / 8;

    // ---- CSR build + fp16 convert (fused extra blocks)
    hipMemsetAsync(deg, 0, (char*)(cnt + N_NODES) - (char*)deg, stream);
    deg_hist_conv_kernel<<<eb + cb, 256, 0, stream>>>(col, w, deg, cnt, E, eb, x, xh);
    scan_kernel<<<1, 1024, 0, stream>>>(cnt, rowptr, cur, N_NODES);
    fill_kernel<<<eb, 256, 0, stream>>>(row, col, w, deg, cur, edge_s, E);

    // ---- layer 1: aggregate xh -> aggx (fp32 chunked), fused MLP -> y2h (fp16 chunked)
    gather_agg_kernel<false><<<nb, 256, 0, stream>>>(rowptr, edge_s, xh, nullptr, aggx, N_NODES);
    mlp_kernel<<<cb, 256, 0, stream>>>(aggx, W1, b1, W2, y2h);

    // ---- layer 2: aggregate y2h with fused tanh(acc + b2) -> out fp32 [t][n][f]
    gather_agg_kernel<true><<<nb, 256, 0, stream>>>(rowptr, edge_s, y2h, b2, out, N_NODES);
}

// Round 7
// 176.498 us; speedup vs baseline: 7.0402x; 1.0004x over previous
//
#include <hip/hip_runtime.h>
#include <hip/hip_fp16.h>

#define T_DIM   12
#define N_NODES 10000
#define F_IN    32
#define H_DIM   64
#define NCH     3            // t-chunks
#define TC      4            // timesteps per chunk
#define CHROW   (TC * F_IN)  // elements per node per chunk = 128
#define NGRP    (N_NODES / 16)        // 625 node-groups of 16
#define NTASK   (NCH * NGRP)          // 1875 wave tasks
#define NROWS   (NCH * N_NODES * TC)  // 120000 (n,t) rows
#define MROWS   128                   // rows per mlp block

// ------------------------------------------------ fused: degree+histogram (blocks [0,eb)) and
// x fp32 [t][n][f] -> xh fp16 chunked [ch][n][tc][f] (blocks [eb, eb+cb)), wave-aligned mapping
__global__ void deg_hist_conv_kernel(const int* __restrict__ col,
                                     const float* __restrict__ w,
                                     float* __restrict__ deg,
                                     int* __restrict__ cnt, int E, int eb,
                                     const float* __restrict__ x,
                                     __half* __restrict__ xh) {
    int b = blockIdx.x;
    if (b < eb) {
        int e = b * 256 + threadIdx.x;
        if (e >= E) return;
        int c = col[e];
        atomicAdd(&deg[c], w[e]);
        atomicAdd(&cnt[c], 1);
    } else {
        int task = (b - eb) * 4 + (threadIdx.x >> 6);
        if (task >= NTASK) return;
        int l  = threadIdx.x & 63;
        int ch = task / NGRP;
        int ng = task - ch * NGRP;
        int n  = ng * 16 + (l >> 2);
        int t  = ch * TC + (l & 3);
        const float4* xp = (const float4*)(x + ((size_t)t * N_NODES + n) * F_IN);
        union { uint32_t u[16]; uint4 q[4]; } pk;
#pragma unroll
        for (int i = 0; i < 8; i++) {
            float4 v = xp[i];
            __half2 h0 = __floats2half2_rn(v.x, v.y);
            __half2 h1 = __floats2half2_rn(v.z, v.w);
            pk.u[2 * i]     = *(uint32_t*)&h0;
            pk.u[2 * i + 1] = *(uint32_t*)&h1;
        }
        uint4* dp = (uint4*)(xh + ((size_t)ch * N_NODES * TC + ng * 64 + l) * F_IN);
#pragma unroll
        for (int i = 0; i < 4; i++) dp[i] = pk.q[i];
    }
}

// ------------------------------------------------ single-block exclusive scan -> rowptr, seed cur
__global__ __launch_bounds__(1024) void scan_kernel(const int* __restrict__ cnt,
                                                    int* __restrict__ rowptr,
                                                    int* __restrict__ cur, int n) {
    __shared__ int part[1024];
    int tid = threadIdx.x;
    const int per = (n + 1023) / 1024;
    int base = tid * per;
    int s = 0;
    for (int i = 0; i < per; i++) {
        int idx = base + i;
        if (idx < n) s += cnt[idx];
    }
    part[tid] = s;
    __syncthreads();
    for (int off = 1; off < 1024; off <<= 1) {
        int v = 0;
        if (tid >= off) v = part[tid - off];
        __syncthreads();
        if (tid >= off) part[tid] += v;
        __syncthreads();
    }
    int run = (tid == 0) ? 0 : part[tid - 1];
    for (int i = 0; i < per; i++) {
        int idx = base + i;
        if (idx < n) { rowptr[idx] = run; cur[idx] = run; run += cnt[idx]; }
    }
    if (tid == 1023) rowptr[n] = part[1023];
}

// ------------------------------------------------ fill: norm inline, bucket-sort edges by dst
__global__ void fill_kernel(const int* __restrict__ row,
                            const int* __restrict__ col,
                            const float* __restrict__ w,
                            const float* __restrict__ deg,
                            int* __restrict__ cur,
                            int2* __restrict__ edge_s, int E) {
    int e = blockIdx.x * blockDim.x + threadIdx.x;
    if (e >= E) return;
    int r = row[e];
    int c = col[e];
    float dr = deg[r];
    float dc = deg[c];
    float ir = dr > 0.f ? 1.0f / sqrtf(fmaxf(dr, 1e-12f)) : 0.f;
    float ic = dc > 0.f ? 1.0f / sqrtf(fmaxf(dc, 1e-12f)) : 0.f;
    float nw = ir * w[e] * ic;
    int pos = atomicAdd(&cur[c], 1);   // cur pre-seeded with rowptr starts
    edge_s[pos] = make_int2(r, __float_as_int(nw));
}

// ------------------------------------------------ CSR gather-aggregate from fp16 chunked source.
// 32 lanes per dst node; per edge per chunk ONE dwordx2/lane (256 B contiguous node row).
// TANH=false: write fp32 chunked row-linear [(ch*N + n)*4 + tc][f].
// TANH=true : write fp32 standard [t][n][f] with fused tanh(acc+bias).
template <bool TANH>
__global__ __launch_bounds__(256) void gather_agg_kernel(const int* __restrict__ rowptr,
                                                         const int2* __restrict__ edge_s,
                                                         const __half* __restrict__ yh,
                                                         const float* __restrict__ bias,
                                                         float* __restrict__ outp, int n) {
    int c = blockIdx.x * 8 + (threadIdx.x >> 5);
    if (c >= n) return;
    int l = threadIdx.x & 31;           // lane: tc = l>>3, f-quad = l&7 -> fp16 offset 4*l

    int beg = rowptr[c], end = rowptr[c + 1];
    float4 b4 = {0.f, 0.f, 0.f, 0.f};
    if (TANH) b4 = *(const float4*)(bias + 4 * (l & 7));

#pragma unroll
    for (int ch = 0; ch < NCH; ch++) {
        const __half* base = yh + (size_t)ch * N_NODES * CHROW + 4 * l;
        float4 a = {0.f, 0.f, 0.f, 0.f};
#pragma unroll 8
        for (int e = beg; e < end; e++) {
            int2 ed = edge_s[e];
            float nw = __int_as_float(ed.y);
            uint2 u = *(const uint2*)(base + (size_t)ed.x * CHROW);
            __half2 h0 = *(__half2*)&u.x;
            __half2 h1 = *(__half2*)&u.y;
            float2 f0 = __half22float2(h0);
            float2 f1 = __half22float2(h1);
            a.x = fmaf(f0.x, nw, a.x);
            a.y = fmaf(f0.y, nw, a.y);
            a.z = fmaf(f1.x, nw, a.z);
            a.w = fmaf(f1.y, nw, a.w);
        }
        if (TANH) {
            a.x = tanhf(a.x + b4.x); a.y = tanhf(a.y + b4.y);
            a.z = tanhf(a.z + b4.z); a.w = tanhf(a.w + b4.w);
            float* op = outp + ((size_t)(ch * TC + (l >> 3)) * N_NODES + c) * F_IN + 4 * (l & 7);
            *(float4*)op = a;
        } else {
            float* op = outp + ((size_t)ch * N_NODES + c) * CHROW + 4 * l;
            *(float4*)op = a;
        }
    }
}

// ------------------------------------------------ fused MLP: y2 = relu(aggx @ W1 + b1) @ W2.
// Register-blocked tile GEMM: 128 rows/block, 128 threads; thread = 4 rows x 16 cols (stage 1)
// then 4 rows x 8 cols (stage 2). x and h staged in LDS with +1-padded stride (avoids the
// 16-way bank conflict of power-of-2 strides on k-streaming reads; 2-way is free).
__global__ __launch_bounds__(128) void mlp_kernel(const float* __restrict__ aggx,
                                                  const float* __restrict__ W1g,
                                                  const float* __restrict__ b1,
                                                  const float* __restrict__ W2g,
                                                  __half* __restrict__ y2h) {
    __shared__ float W1s[F_IN * H_DIM];            // 8 KB
    __shared__ float W2s[H_DIM * F_IN];            // 8 KB
    __shared__ float b1s[H_DIM];
    __shared__ float xs[MROWS][F_IN + 1];          // 16.9 KB
    __shared__ float hs[MROWS][H_DIM + 1];         // 33.3 KB

    int tid = threadIdx.x;
    for (int i = tid; i < F_IN * H_DIM; i += 128) { W1s[i] = W1g[i]; W2s[i] = W2g[i]; }
    if (tid < H_DIM) b1s[tid] = b1[tid];

    // stage x: 128 rows x 32 floats, linear 16 KB copy
    size_t row0 = (size_t)blockIdx.x * MROWS;
    const float4* src = (const float4*)(aggx + row0 * F_IN);
    for (int i = tid; i < MROWS * (F_IN / 4); i += 128) {
        float4 v = src[i];
        int r = i >> 3, q = (i & 7) * 4;
        xs[r][q + 0] = v.x; xs[r][q + 1] = v.y; xs[r][q + 2] = v.z; xs[r][q + 3] = v.w;
    }
    __syncthreads();

    int rg = tid >> 2;          // row group: rows 4*rg .. 4*rg+3
    int cg = tid & 3;
    int r0 = 4 * rg;

    // ---- stage 1: h = relu(x @ W1 + b1), cols 16*cg .. +15
    {
        int c0 = 16 * cg;
        float acc[4][16];
#pragma unroll
        for (int j = 0; j < 16; j++) {
            float b = b1s[c0 + j];
#pragma unroll
            for (int rr = 0; rr < 4; rr++) acc[rr][j] = b;
        }
#pragma unroll 8
        for (int k = 0; k < F_IN; k++) {
            float xr[4];
#pragma unroll
            for (int rr = 0; rr < 4; rr++) xr[rr] = xs[r0 + rr][k];
#pragma unroll
            for (int j = 0; j < 16; j++) {
                float wv = W1s[k * H_DIM + c0 + j];
#pragma unroll
                for (int rr = 0; rr < 4; rr++) acc[rr][j] = fmaf(xr[rr], wv, acc[rr][j]);
            }
        }
#pragma unroll
        for (int rr = 0; rr < 4; rr++)
#pragma unroll
            for (int j = 0; j < 16; j++)
                hs[r0 + rr][c0 + j] = fmaxf(acc[rr][j], 0.f);
    }
    __syncthreads();

    // ---- stage 2: o = h @ W2, cols 8*cg .. +7
    {
        int d0 = 8 * cg;
        float acc[4][8];
#pragma unroll
        for (int rr = 0; rr < 4; rr++)
#pragma unroll
            for (int j = 0; j < 8; j++) acc[rr][j] = 0.f;
#pragma unroll 8
        for (int k = 0; k < H_DIM; k++) {
            float hr[4];
#pragma unroll
            for (int rr = 0; rr < 4; rr++) hr[rr] = hs[r0 + rr][k];
#pragma unroll
            for (int j = 0; j < 8; j++) {
                float wv = W2s[k * F_IN + d0 + j];
#pragma unroll
                for (int rr = 0; rr < 4; rr++) acc[rr][j] = fmaf(hr[rr], wv, acc[rr][j]);
            }
        }
        // pack fp16, write 16 B per row
#pragma unroll
        for (int rr = 0; rr < 4; rr++) {
            union { uint32_t u[4]; uint4 q; } pk;
#pragma unroll
            for (int i = 0; i < 4; i++) {
                __half2 hh = __floats2half2_rn(acc[rr][2 * i], acc[rr][2 * i + 1]);
                pk.u[i] = *(uint32_t*)&hh;
            }
            *(uint4*)(y2h + (row0 + r0 + rr) * F_IN + d0) = pk.q;
        }
    }
}

// ----------------------------------------------------------------
extern "C" void kernel_launch(void* const* d_in, const int* in_sizes, int n_in,
                              void* d_out, int out_size, void* d_ws, size_t ws_size,
                              hipStream_t stream) {
    const float* x  = (const float*)d_in[0];
    const int*   ei = (const int*)d_in[1];
    const float* w  = (const float*)d_in[2];
    // d_in[3] = missing_mask (unused)
    const float* W1 = (const float*)d_in[4];
    const float* b1 = (const float*)d_in[5];
    const float* W2 = (const float*)d_in[6];
    const float* b2 = (const float*)d_in[7];
    float* out = (float*)d_out;

    const int E = in_sizes[1] / 2;
    const int* row = ei;
    const int* col = ei + E;

    char* ws = (char*)d_ws;
    size_t off = 0;
    auto alloc = [&](size_t bytes) { void* p = ws + off; off += (bytes + 255) & ~(size_t)255; return p; };
    float*  deg    = (float*) alloc(N_NODES * sizeof(float));
    int*    cnt    = (int*)   alloc(N_NODES * sizeof(int));
    int*    cur    = (int*)   alloc(N_NODES * sizeof(int));
    int*    rowptr = (int*)   alloc((N_NODES + 1) * sizeof(int));
    int2*   edge_s = (int2*)  alloc((size_t)E * sizeof(int2));                              // 2.56 MB
    __half* xh     = (__half*)alloc((size_t)NROWS * F_IN * sizeof(__half));                 // 7.68 MB
    // +64 rows slack so the last mlp block (rows 119936..120063) runs unguarded
    __half* y2h    = (__half*)alloc((size_t)(NROWS + 64) * F_IN * sizeof(__half));
    float*  aggx   = (float*) alloc((size_t)(NROWS + 64) * F_IN * sizeof(float));           // 15.4 MB

    const int eb = (E + 255) / 256;
    const int cb = (NTASK + 3) / 4;
    const int nb = (N_NODES + 7) / 8;
    const int mb = (NROWS + MROWS - 1) / MROWS;   // 938

    // ---- CSR build + fp16 convert (fused extra blocks)
    hipMemsetAsync(deg, 0, (char*)(cnt + N_NODES) - (char*)deg, stream);
    deg_hist_conv_kernel<<<eb + cb, 256, 0, stream>>>(col, w, deg, cnt, E, eb, x, xh);
    scan_kernel<<<1, 1024, 0, stream>>>(cnt, rowptr, cur, N_NODES);
    fill_kernel<<<eb, 256, 0, stream>>>(row, col, w, deg, cur, edge_s, E);

    // ---- layer 1: aggregate xh -> aggx (fp32 chunk-row-linear), tiled MLP -> y2h (fp16)
    gather_agg_kernel<false><<<nb, 256, 0, stream>>>(rowptr, edge_s, xh, nullptr, aggx, N_NODES);
    mlp_kernel<<<mb, 128, 0, stream>>>(aggx, W1, b1, W2, y2h);

    // ---- layer 2: aggregate y2h with fused tanh(acc + b2) -> out fp32 [t][n][f]
    gather_agg_kernel<true><<<nb, 256, 0, stream>>>(rowptr, edge_s, y2h, b2, out, N_NODES);
}

// Round 8
// 169.804 us; speedup vs baseline: 7.3178x; 1.0394x over previous
//
#include <hip/hip_runtime.h>
#include <hip/hip_fp16.h>

#define T_DIM   12
#define N_NODES 10000
#define F_IN    32
#define H_DIM   64
#define NCH     3            // t-chunks
#define TC      4            // timesteps per chunk
#define CHROW   (TC * F_IN)  // elements per node per chunk = 128
#define NGRP    (N_NODES / 16)        // 625 node-groups of 16
#define NTASK   (NCH * NGRP)          // 1875 wave tasks
#define NROWS   (NCH * N_NODES * TC)  // 120000 (n,t) rows
#define MROWS   128                   // rows per mlp block

// ------------------------------------------------ zero deg+cnt (replaces 42us runtime fill)
__global__ void zero_kernel(uint4* __restrict__ p, int n16) {
    int i = blockIdx.x * blockDim.x + threadIdx.x;
    if (i < n16) p[i] = make_uint4(0, 0, 0, 0);
}

// ------------------------------------------------ fused: degree+histogram (blocks [0,eb)) and
// x fp32 [t][n][f] -> xh fp16 chunked [ch][n][tc][f] (blocks [eb, eb+cb)), wave-aligned mapping
__global__ void deg_hist_conv_kernel(const int* __restrict__ col,
                                     const float* __restrict__ w,
                                     float* __restrict__ deg,
                                     int* __restrict__ cnt, int E, int eb,
                                     const float* __restrict__ x,
                                     __half* __restrict__ xh) {
    int b = blockIdx.x;
    if (b < eb) {
        int e = b * 256 + threadIdx.x;
        if (e >= E) return;
        int c = col[e];
        atomicAdd(&deg[c], w[e]);
        atomicAdd(&cnt[c], 1);
    } else {
        int task = (b - eb) * 4 + (threadIdx.x >> 6);
        if (task >= NTASK) return;
        int l  = threadIdx.x & 63;
        int ch = task / NGRP;
        int ng = task - ch * NGRP;
        int n  = ng * 16 + (l >> 2);
        int t  = ch * TC + (l & 3);
        const float4* xp = (const float4*)(x + ((size_t)t * N_NODES + n) * F_IN);
        union { uint32_t u[16]; uint4 q[4]; } pk;
#pragma unroll
        for (int i = 0; i < 8; i++) {
            float4 v = xp[i];
            __half2 h0 = __floats2half2_rn(v.x, v.y);
            __half2 h1 = __floats2half2_rn(v.z, v.w);
            pk.u[2 * i]     = *(uint32_t*)&h0;
            pk.u[2 * i + 1] = *(uint32_t*)&h1;
        }
        uint4* dp = (uint4*)(xh + ((size_t)ch * N_NODES * TC + ng * 64 + l) * F_IN);
#pragma unroll
        for (int i = 0; i < 4; i++) dp[i] = pk.q[i];
    }
}

// ------------------------------------------------ single-block exclusive scan -> rowptr, seed cur
__global__ __launch_bounds__(1024) void scan_kernel(const int* __restrict__ cnt,
                                                    int* __restrict__ rowptr,
                                                    int* __restrict__ cur, int n) {
    __shared__ int part[1024];
    int tid = threadIdx.x;
    const int per = (n + 1023) / 1024;
    int base = tid * per;
    int s = 0;
    for (int i = 0; i < per; i++) {
        int idx = base + i;
        if (idx < n) s += cnt[idx];
    }
    part[tid] = s;
    __syncthreads();
    for (int off = 1; off < 1024; off <<= 1) {
        int v = 0;
        if (tid >= off) v = part[tid - off];
        __syncthreads();
        if (tid >= off) part[tid] += v;
        __syncthreads();
    }
    int run = (tid == 0) ? 0 : part[tid - 1];
    for (int i = 0; i < per; i++) {
        int idx = base + i;
        if (idx < n) { rowptr[idx] = run; cur[idx] = run; run += cnt[idx]; }
    }
    if (tid == 1023) rowptr[n] = part[1023];
}

// ------------------------------------------------ fill: norm inline, bucket-sort edges by dst
__global__ void fill_kernel(const int* __restrict__ row,
                            const int* __restrict__ col,
                            const float* __restrict__ w,
                            const float* __restrict__ deg,
                            int* __restrict__ cur,
                            int2* __restrict__ edge_s, int E) {
    int e = blockIdx.x * blockDim.x + threadIdx.x;
    if (e >= E) return;
    int r = row[e];
    int c = col[e];
    float dr = deg[r];
    float dc = deg[c];
    float ir = dr > 0.f ? 1.0f / sqrtf(fmaxf(dr, 1e-12f)) : 0.f;
    float ic = dc > 0.f ? 1.0f / sqrtf(fmaxf(dc, 1e-12f)) : 0.f;
    float nw = ir * w[e] * ic;
    int pos = atomicAdd(&cur[c], 1);   // cur pre-seeded with rowptr starts
    edge_s[pos] = make_int2(r, __float_as_int(nw));
}

// ------------------------------------------------ A: single-pass gather (edge read once,
// 3 independent 8B loads per edge). Writes fp32 chunk-row-linear.
__global__ __launch_bounds__(256) void gather_sp_kernel(const int* __restrict__ rowptr,
                                                        const int2* __restrict__ edge_s,
                                                        const __half* __restrict__ yh,
                                                        float* __restrict__ outp, int n) {
    int c = blockIdx.x * 8 + (threadIdx.x >> 5);
    if (c >= n) return;
    int l = threadIdx.x & 31;           // tc = l>>3, f-quad = l&7 -> fp16 offset 4*l

    int beg = rowptr[c], end = rowptr[c + 1];
    const __half* base = yh + 4 * l;
    const size_t cstep = (size_t)N_NODES * CHROW;

    float4 a0 = {0.f, 0.f, 0.f, 0.f};
    float4 a1 = {0.f, 0.f, 0.f, 0.f};
    float4 a2 = {0.f, 0.f, 0.f, 0.f};

#pragma unroll 4
    for (int e = beg; e < end; e++) {
        int2 ed = edge_s[e];
        float nw = __int_as_float(ed.y);
        const __half* p = base + (size_t)ed.x * CHROW;
        uint2 u0 = *(const uint2*)(p);
        uint2 u1 = *(const uint2*)(p + cstep);
        uint2 u2 = *(const uint2*)(p + 2 * cstep);
        float2 f00 = __half22float2(*(__half2*)&u0.x), f01 = __half22float2(*(__half2*)&u0.y);
        float2 f10 = __half22float2(*(__half2*)&u1.x), f11 = __half22float2(*(__half2*)&u1.y);
        float2 f20 = __half22float2(*(__half2*)&u2.x), f21 = __half22float2(*(__half2*)&u2.y);
        a0.x = fmaf(f00.x, nw, a0.x); a0.y = fmaf(f00.y, nw, a0.y);
        a0.z = fmaf(f01.x, nw, a0.z); a0.w = fmaf(f01.y, nw, a0.w);
        a1.x = fmaf(f10.x, nw, a1.x); a1.y = fmaf(f10.y, nw, a1.y);
        a1.z = fmaf(f11.x, nw, a1.z); a1.w = fmaf(f11.y, nw, a1.w);
        a2.x = fmaf(f20.x, nw, a2.x); a2.y = fmaf(f20.y, nw, a2.y);
        a2.z = fmaf(f21.x, nw, a2.z); a2.w = fmaf(f21.y, nw, a2.w);
    }

    float* op = outp + (size_t)c * CHROW + 4 * l;
    const size_t ostep = (size_t)N_NODES * CHROW;
    *(float4*)(op)             = a0;
    *(float4*)(op + ostep)     = a1;
    *(float4*)(op + 2 * ostep) = a2;
}

// ------------------------------------------------ B: chunked 3-pass gather (L2-resident chunk),
// fused tanh(acc+bias), writes fp32 standard [t][n][f].
__global__ __launch_bounds__(256) void gather_ch_kernel(const int* __restrict__ rowptr,
                                                        const int2* __restrict__ edge_s,
                                                        const __half* __restrict__ yh,
                                                        const float* __restrict__ bias,
                                                        float* __restrict__ outp, int n) {
    int c = blockIdx.x * 8 + (threadIdx.x >> 5);
    if (c >= n) return;
    int l = threadIdx.x & 31;

    int beg = rowptr[c], end = rowptr[c + 1];
    float4 b4 = *(const float4*)(bias + 4 * (l & 7));

#pragma unroll
    for (int ch = 0; ch < NCH; ch++) {
        const __half* base = yh + (size_t)ch * N_NODES * CHROW + 4 * l;
        float4 a = {0.f, 0.f, 0.f, 0.f};
#pragma unroll 8
        for (int e = beg; e < end; e++) {
            int2 ed = edge_s[e];
            float nw = __int_as_float(ed.y);
            uint2 u = *(const uint2*)(base + (size_t)ed.x * CHROW);
            float2 f0 = __half22float2(*(__half2*)&u.x);
            float2 f1 = __half22float2(*(__half2*)&u.y);
            a.x = fmaf(f0.x, nw, a.x);
            a.y = fmaf(f0.y, nw, a.y);
            a.z = fmaf(f1.x, nw, a.z);
            a.w = fmaf(f1.y, nw, a.w);
        }
        a.x = tanhf(a.x + b4.x); a.y = tanhf(a.y + b4.y);
        a.z = tanhf(a.z + b4.z); a.w = tanhf(a.w + b4.w);
        float* op = outp + ((size_t)(ch * TC + (l >> 3)) * N_NODES + c) * F_IN + 4 * (l & 7);
        *(float4*)op = a;
    }
}

// ------------------------------------------------ fused MLP: register-blocked tile GEMM
__global__ __launch_bounds__(128) void mlp_kernel(const float* __restrict__ aggx,
                                                  const float* __restrict__ W1g,
                                                  const float* __restrict__ b1,
                                                  const float* __restrict__ W2g,
                                                  __half* __restrict__ y2h) {
    __shared__ float W1s[F_IN * H_DIM];
    __shared__ float W2s[H_DIM * F_IN];
    __shared__ float b1s[H_DIM];
    __shared__ float xs[MROWS][F_IN + 1];
    __shared__ float hs[MROWS][H_DIM + 1];

    int tid = threadIdx.x;
    for (int i = tid; i < F_IN * H_DIM; i += 128) { W1s[i] = W1g[i]; W2s[i] = W2g[i]; }
    if (tid < H_DIM) b1s[tid] = b1[tid];

    size_t row0 = (size_t)blockIdx.x * MROWS;
    const float4* src = (const float4*)(aggx + row0 * F_IN);
    for (int i = tid; i < MROWS * (F_IN / 4); i += 128) {
        float4 v = src[i];
        int r = i >> 3, q = (i & 7) * 4;
        xs[r][q + 0] = v.x; xs[r][q + 1] = v.y; xs[r][q + 2] = v.z; xs[r][q + 3] = v.w;
    }
    __syncthreads();

    int rg = tid >> 2;
    int cg = tid & 3;
    int r0 = 4 * rg;

    {
        int c0 = 16 * cg;
        float acc[4][16];
#pragma unroll
        for (int j = 0; j < 16; j++) {
            float b = b1s[c0 + j];
#pragma unroll
            for (int rr = 0; rr < 4; rr++) acc[rr][j] = b;
        }
#pragma unroll 8
        for (int k = 0; k < F_IN; k++) {
            float xr[4];
#pragma unroll
            for (int rr = 0; rr < 4; rr++) xr[rr] = xs[r0 + rr][k];
#pragma unroll
            for (int j = 0; j < 16; j++) {
                float wv = W1s[k * H_DIM + c0 + j];
#pragma unroll
                for (int rr = 0; rr < 4; rr++) acc[rr][j] = fmaf(xr[rr], wv, acc[rr][j]);
            }
        }
#pragma unroll
        for (int rr = 0; rr < 4; rr++)
#pragma unroll
            for (int j = 0; j < 16; j++)
                hs[r0 + rr][c0 + j] = fmaxf(acc[rr][j], 0.f);
    }
    __syncthreads();

    {
        int d0 = 8 * cg;
        float acc[4][8];
#pragma unroll
        for (int rr = 0; rr < 4; rr++)
#pragma unroll
            for (int j = 0; j < 8; j++) acc[rr][j] = 0.f;
#pragma unroll 8
        for (int k = 0; k < H_DIM; k++) {
            float hr[4];
#pragma unroll
            for (int rr = 0; rr < 4; rr++) hr[rr] = hs[r0 + rr][k];
#pragma unroll
            for (int j = 0; j < 8; j++) {
                float wv = W2s[k * F_IN + d0 + j];
#pragma unroll
                for (int rr = 0; rr < 4; rr++) acc[rr][j] = fmaf(hr[rr], wv, acc[rr][j]);
            }
        }
#pragma unroll
        for (int rr = 0; rr < 4; rr++) {
            union { uint32_t u[4]; uint4 q; } pk;
#pragma unroll
            for (int i = 0; i < 4; i++) {
                __half2 hh = __floats2half2_rn(acc[rr][2 * i], acc[rr][2 * i + 1]);
                pk.u[i] = *(uint32_t*)&hh;
            }
            *(uint4*)(y2h + (row0 + r0 + rr) * F_IN + d0) = pk.q;
        }
    }
}

// ----------------------------------------------------------------
extern "C" void kernel_launch(void* const* d_in, const int* in_sizes, int n_in,
                              void* d_out, int out_size, void* d_ws, size_t ws_size,
                              hipStream_t stream) {
    const float* x  = (const float*)d_in[0];
    const int*   ei = (const int*)d_in[1];
    const float* w  = (const float*)d_in[2];
    // d_in[3] = missing_mask (unused)
    const float* W1 = (const float*)d_in[4];
    const float* b1 = (const float*)d_in[5];
    const float* W2 = (const float*)d_in[6];
    const float* b2 = (const float*)d_in[7];
    float* out = (float*)d_out;

    const int E = in_sizes[1] / 2;
    const int* row = ei;
    const int* col = ei + E;

    char* ws = (char*)d_ws;
    size_t off = 0;
    auto alloc = [&](size_t bytes) { void* p = ws + off; off += (bytes + 255) & ~(size_t)255; return p; };
    float*  deg    = (float*) alloc(N_NODES * sizeof(float));
    int*    cnt    = (int*)   alloc(N_NODES * sizeof(int));
    int*    cur    = (int*)   alloc(N_NODES * sizeof(int));
    int*    rowptr = (int*)   alloc((N_NODES + 1) * sizeof(int));
    int2*   edge_s = (int2*)  alloc((size_t)E * sizeof(int2));
    __half* xh     = (__half*)alloc((size_t)NROWS * F_IN * sizeof(__half));
    __half* y2h    = (__half*)alloc((size_t)(NROWS + 64) * F_IN * sizeof(__half));
    float*  aggx   = (float*) alloc((size_t)(NROWS + 64) * F_IN * sizeof(float));

    const int eb = (E + 255) / 256;
    const int cb = (NTASK + 3) / 4;
    const int nb = (N_NODES + 7) / 8;
    const int mb = (NROWS + MROWS - 1) / MROWS;

    // ---- CSR build + fp16 convert
    const int zn = (int)(((char*)(cnt + N_NODES) - (char*)deg) / 16);   // uint4 count (256B-aligned region)
    zero_kernel<<<(zn + 255) / 256, 256, 0, stream>>>((uint4*)deg, zn);
    deg_hist_conv_kernel<<<eb + cb, 256, 0, stream>>>(col, w, deg, cnt, E, eb, x, xh);
    scan_kernel<<<1, 1024, 0, stream>>>(cnt, rowptr, cur, N_NODES);
    fill_kernel<<<eb, 256, 0, stream>>>(row, col, w, deg, cur, edge_s, E);

    // ---- layer 1: single-pass gather (A/B probe vs chunked gather2), tiled MLP
    gather_sp_kernel<<<nb, 256, 0, stream>>>(rowptr, edge_s, xh, aggx, N_NODES);
    mlp_kernel<<<mb, 128, 0, stream>>>(aggx, W1, b1, W2, y2h);

    // ---- layer 2: chunked gather with fused tanh(acc + b2)
    gather_ch_kernel<<<nb, 256, 0, stream>>>(rowptr, edge_s, y2h, b2, out, N_NODES);
}

// Round 9
// 165.774 us; speedup vs baseline: 7.4957x; 1.0243x over previous
//
#include <hip/hip_runtime.h>
#include <hip/hip_fp16.h>

#define T_DIM   12
#define N_NODES 10000
#define F_IN    32
#define H_DIM   64
#define NCH     3            // t-chunks
#define TC      4            // timesteps per chunk
#define CHROW   (TC * F_IN)  // fp16/fp32 elements per node per chunk = 128
#define NGRP    (N_NODES / 16)
#define NTASK   (NCH * NGRP)
#define NROWS   (NCH * N_NODES * TC)  // 120000 (n,t) rows
#define MROWS   128                   // rows per mlp block

// ------------------------------------------------ zero deg+cnt
__global__ void zero_kernel(uint4* __restrict__ p, int n16) {
    int i = blockIdx.x * blockDim.x + threadIdx.x;
    if (i < n16) p[i] = make_uint4(0, 0, 0, 0);
}

// ------------------------------------------------ fused: degree+histogram (blocks [0,eb)) and
// x fp32 [t][n][f] -> xh fp16 chunked [ch][n][tc][f] (blocks [eb, eb+cb))
__global__ void deg_hist_conv_kernel(const int* __restrict__ col,
                                     const float* __restrict__ w,
                                     float* __restrict__ deg,
                                     int* __restrict__ cnt, int E, int eb,
                                     const float* __restrict__ x,
                                     __half* __restrict__ xh) {
    int b = blockIdx.x;
    if (b < eb) {
        int e = b * 256 + threadIdx.x;
        if (e >= E) return;
        int c = col[e];
        atomicAdd(&deg[c], w[e]);
        atomicAdd(&cnt[c], 1);
    } else {
        int task = (b - eb) * 4 + (threadIdx.x >> 6);
        if (task >= NTASK) return;
        int l  = threadIdx.x & 63;
        int ch = task / NGRP;
        int ng = task - ch * NGRP;
        int n  = ng * 16 + (l >> 2);
        int t  = ch * TC + (l & 3);
        const float4* xp = (const float4*)(x + ((size_t)t * N_NODES + n) * F_IN);
        union { uint32_t u[16]; uint4 q[4]; } pk;
#pragma unroll
        for (int i = 0; i < 8; i++) {
            float4 v = xp[i];
            __half2 h0 = __floats2half2_rn(v.x, v.y);
            __half2 h1 = __floats2half2_rn(v.z, v.w);
            pk.u[2 * i]     = *(uint32_t*)&h0;
            pk.u[2 * i + 1] = *(uint32_t*)&h1;
        }
        uint4* dp = (uint4*)(xh + ((size_t)ch * N_NODES * TC + ng * 64 + l) * F_IN);
#pragma unroll
        for (int i = 0; i < 4; i++) dp[i] = pk.q[i];
    }
}

// ------------------------------------------------ single-block exclusive scan -> rowptr, seed cur
__global__ __launch_bounds__(1024) void scan_kernel(const int* __restrict__ cnt,
                                                    int* __restrict__ rowptr,
                                                    int* __restrict__ cur, int n) {
    __shared__ int part[1024];
    int tid = threadIdx.x;
    const int per = (n + 1023) / 1024;
    int base = tid * per;
    int s = 0;
    for (int i = 0; i < per; i++) {
        int idx = base + i;
        if (idx < n) s += cnt[idx];
    }
    part[tid] = s;
    __syncthreads();
    for (int off = 1; off < 1024; off <<= 1) {
        int v = 0;
        if (tid >= off) v = part[tid - off];
        __syncthreads();
        if (tid >= off) part[tid] += v;
        __syncthreads();
    }
    int run = (tid == 0) ? 0 : part[tid - 1];
    for (int i = 0; i < per; i++) {
        int idx = base + i;
        if (idx < n) { rowptr[idx] = run; cur[idx] = run; run += cnt[idx]; }
    }
    if (tid == 1023) rowptr[n] = part[1023];
}

// ------------------------------------------------ fill: norm inline, bucket-sort edges by dst
__global__ void fill_kernel(const int* __restrict__ row,
                            const int* __restrict__ col,
                            const float* __restrict__ w,
                            const float* __restrict__ deg,
                            int* __restrict__ cur,
                            int2* __restrict__ edge_s, int E) {
    int e = blockIdx.x * blockDim.x + threadIdx.x;
    if (e >= E) return;
    int r = row[e];
    int c = col[e];
    float dr = deg[r];
    float dc = deg[c];
    float ir = dr > 0.f ? 1.0f / sqrtf(fmaxf(dr, 1e-12f)) : 0.f;
    float ic = dc > 0.f ? 1.0f / sqrtf(fmaxf(dc, 1e-12f)) : 0.f;
    float nw = ir * w[e] * ic;
    int pos = atomicAdd(&cur[c], 1);
    edge_s[pos] = make_int2(r, __float_as_int(nw));
}

// ------------------------------------------------ 64-lane-per-node single-pass gather.
// Two 32-lane halves split the edge list (stride 2), combine via shfl_xor(32).
// Epilogue split: half 0 handles chunks 0,1; half 1 handles chunk 2.
// TANH=false: write fp32 chunked [ch][n][tc][f]. TANH=true: tanh(acc+bias) -> [t][n][f].
template <bool TANH>
__global__ __launch_bounds__(256) void gather64_kernel(const int* __restrict__ rowptr,
                                                       const int2* __restrict__ edge_s,
                                                       const __half* __restrict__ yh,
                                                       const float* __restrict__ bias,
                                                       float* __restrict__ outp, int n) {
    int c = blockIdx.x * 4 + (threadIdx.x >> 6);
    if (c >= n) return;
    int l    = threadIdx.x & 63;
    int half = l >> 5;
    int l32  = l & 31;          // tc = l32>>3, f-quad = l32&7 -> fp16 offset 4*l32

    int beg = rowptr[c], end = rowptr[c + 1];
    const __half* base = yh + 4 * l32;
    const size_t cstep = (size_t)N_NODES * CHROW;

    float4 a0 = {0.f, 0.f, 0.f, 0.f};
    float4 a1 = {0.f, 0.f, 0.f, 0.f};
    float4 a2 = {0.f, 0.f, 0.f, 0.f};

#pragma unroll 4
    for (int e = beg + half; e < end; e += 2) {
        int2 ed = edge_s[e];
        float nw = __int_as_float(ed.y);
        const __half* p = base + (size_t)ed.x * CHROW;
        uint2 u0 = *(const uint2*)(p);
        uint2 u1 = *(const uint2*)(p + cstep);
        uint2 u2 = *(const uint2*)(p + 2 * cstep);
        float2 f00 = __half22float2(*(__half2*)&u0.x), f01 = __half22float2(*(__half2*)&u0.y);
        float2 f10 = __half22float2(*(__half2*)&u1.x), f11 = __half22float2(*(__half2*)&u1.y);
        float2 f20 = __half22float2(*(__half2*)&u2.x), f21 = __half22float2(*(__half2*)&u2.y);
        a0.x = fmaf(f00.x, nw, a0.x); a0.y = fmaf(f00.y, nw, a0.y);
        a0.z = fmaf(f01.x, nw, a0.z); a0.w = fmaf(f01.y, nw, a0.w);
        a1.x = fmaf(f10.x, nw, a1.x); a1.y = fmaf(f10.y, nw, a1.y);
        a1.z = fmaf(f11.x, nw, a1.z); a1.w = fmaf(f11.y, nw, a1.w);
        a2.x = fmaf(f20.x, nw, a2.x); a2.y = fmaf(f20.y, nw, a2.y);
        a2.z = fmaf(f21.x, nw, a2.z); a2.w = fmaf(f21.y, nw, a2.w);
    }

    // combine halves: full sum lands in both halves
    a0.x += __shfl_xor(a0.x, 32); a0.y += __shfl_xor(a0.y, 32);
    a0.z += __shfl_xor(a0.z, 32); a0.w += __shfl_xor(a0.w, 32);
    a1.x += __shfl_xor(a1.x, 32); a1.y += __shfl_xor(a1.y, 32);
    a1.z += __shfl_xor(a1.z, 32); a1.w += __shfl_xor(a1.w, 32);
    a2.x += __shfl_xor(a2.x, 32); a2.y += __shfl_xor(a2.y, 32);
    a2.z += __shfl_xor(a2.z, 32); a2.w += __shfl_xor(a2.w, 32);

    if (TANH) {
        float4 b4 = *(const float4*)(bias + 4 * (l32 & 7));
        if (half == 0) {
            a0.x = tanhf(a0.x + b4.x); a0.y = tanhf(a0.y + b4.y);
            a0.z = tanhf(a0.z + b4.z); a0.w = tanhf(a0.w + b4.w);
            a1.x = tanhf(a1.x + b4.x); a1.y = tanhf(a1.y + b4.y);
            a1.z = tanhf(a1.z + b4.z); a1.w = tanhf(a1.w + b4.w);
            int t0 = (l32 >> 3);
            float* op0 = outp + ((size_t)t0 * N_NODES + c) * F_IN + 4 * (l32 & 7);
            *(float4*)(op0)                              = a0;
            *(float4*)(op0 + (size_t)TC * N_NODES * F_IN) = a1;
        } else {
            a2.x = tanhf(a2.x + b4.x); a2.y = tanhf(a2.y + b4.y);
            a2.z = tanhf(a2.z + b4.z); a2.w = tanhf(a2.w + b4.w);
            int t2 = 2 * TC + (l32 >> 3);
            float* op2 = outp + ((size_t)t2 * N_NODES + c) * F_IN + 4 * (l32 & 7);
            *(float4*)op2 = a2;
        }
    } else {
        float* op = outp + (size_t)c * CHROW + 4 * l32;
        const size_t ostep = (size_t)N_NODES * CHROW;
        if (half == 0) {
            *(float4*)(op)         = a0;
            *(float4*)(op + ostep) = a1;
        } else {
            *(float4*)(op + 2 * ostep) = a2;
        }
    }
}

// ------------------------------------------------ fused MLP: register-blocked tile GEMM
__global__ __launch_bounds__(128) void mlp_kernel(const float* __restrict__ aggx,
                                                  const float* __restrict__ W1g,
                                                  const float* __restrict__ b1,
                                                  const float* __restrict__ W2g,
                                                  __half* __restrict__ y2h) {
    __shared__ float W1s[F_IN * H_DIM];
    __shared__ float W2s[H_DIM * F_IN];
    __shared__ float b1s[H_DIM];
    __shared__ float xs[MROWS][F_IN + 1];
    __shared__ float hs[MROWS][H_DIM + 1];

    int tid = threadIdx.x;
    for (int i = tid; i < F_IN * H_DIM; i += 128) { W1s[i] = W1g[i]; W2s[i] = W2g[i]; }
    if (tid < H_DIM) b1s[tid] = b1[tid];

    size_t row0 = (size_t)blockIdx.x * MROWS;
    const float4* src = (const float4*)(aggx + row0 * F_IN);
    for (int i = tid; i < MROWS * (F_IN / 4); i += 128) {
        float4 v = src[i];
        int r = i >> 3, q = (i & 7) * 4;
        xs[r][q + 0] = v.x; xs[r][q + 1] = v.y; xs[r][q + 2] = v.z; xs[r][q + 3] = v.w;
    }
    __syncthreads();

    int rg = tid >> 2;
    int cg = tid & 3;
    int r0 = 4 * rg;

    {
        int c0 = 16 * cg;
        float acc[4][16];
#pragma unroll
        for (int j = 0; j < 16; j++) {
            float b = b1s[c0 + j];
#pragma unroll
            for (int rr = 0; rr < 4; rr++) acc[rr][j] = b;
        }
#pragma unroll 8
        for (int k = 0; k < F_IN; k++) {
            float xr[4];
#pragma unroll
            for (int rr = 0; rr < 4; rr++) xr[rr] = xs[r0 + rr][k];
#pragma unroll
            for (int j = 0; j < 16; j++) {
                float wv = W1s[k * H_DIM + c0 + j];
#pragma unroll
                for (int rr = 0; rr < 4; rr++) acc[rr][j] = fmaf(xr[rr], wv, acc[rr][j]);
            }
        }
#pragma unroll
        for (int rr = 0; rr < 4; rr++)
#pragma unroll
            for (int j = 0; j < 16; j++)
                hs[r0 + rr][c0 + j] = fmaxf(acc[rr][j], 0.f);
    }
    __syncthreads();

    {
        int d0 = 8 * cg;
        float acc[4][8];
#pragma unroll
        for (int rr = 0; rr < 4; rr++)
#pragma unroll
            for (int j = 0; j < 8; j++) acc[rr][j] = 0.f;
#pragma unroll 8
        for (int k = 0; k < H_DIM; k++) {
            float hr[4];
#pragma unroll
            for (int rr = 0; rr < 4; rr++) hr[rr] = hs[r0 + rr][k];
#pragma unroll
            for (int j = 0; j < 8; j++) {
                float wv = W2s[k * F_IN + d0 + j];
#pragma unroll
                for (int rr = 0; rr < 4; rr++) acc[rr][j] = fmaf(hr[rr], wv, acc[rr][j]);
            }
        }
#pragma unroll
        for (int rr = 0; rr < 4; rr++) {
            union { uint32_t u[4]; uint4 q; } pk;
#pragma unroll
            for (int i = 0; i < 4; i++) {
                __half2 hh = __floats2half2_rn(acc[rr][2 * i], acc[rr][2 * i + 1]);
                pk.u[i] = *(uint32_t*)&hh;
            }
            *(uint4*)(y2h + (row0 + r0 + rr) * F_IN + d0) = pk.q;
        }
    }
}

// ----------------------------------------------------------------
extern "C" void kernel_launch(void* const* d_in, const int* in_sizes, int n_in,
                              void* d_out, int out_size, void* d_ws, size_t ws_size,
                              hipStream_t stream) {
    const float* x  = (const float*)d_in[0];
    const int*   ei = (const int*)d_in[1];
    const float* w  = (const float*)d_in[2];
    // d_in[3] = missing_mask (unused)
    const float* W1 = (const float*)d_in[4];
    const float* b1 = (const float*)d_in[5];
    const float* W2 = (const float*)d_in[6];
    const float* b2 = (const float*)d_in[7];
    float* out = (float*)d_out;

    const int E = in_sizes[1] / 2;
    const int* row = ei;
    const int* col = ei + E;

    char* ws = (char*)d_ws;
    size_t off = 0;
    auto alloc = [&](size_t bytes) { void* p = ws + off; off += (bytes + 255) & ~(size_t)255; return p; };
    float*  deg    = (float*) alloc(N_NODES * sizeof(float));
    int*    cnt    = (int*)   alloc(N_NODES * sizeof(int));
    int*    cur    = (int*)   alloc(N_NODES * sizeof(int));
    int*    rowptr = (int*)   alloc((N_NODES + 1) * sizeof(int));
    int2*   edge_s = (int2*)  alloc((size_t)E * sizeof(int2));
    __half* xh     = (__half*)alloc((size_t)NROWS * F_IN * sizeof(__half));
    __half* y2h    = (__half*)alloc((size_t)(NROWS + 64) * F_IN * sizeof(__half));
    float*  aggx   = (float*) alloc((size_t)(NROWS + 64) * F_IN * sizeof(float));

    const int eb = (E + 255) / 256;
    const int cb = (NTASK + 3) / 4;
    const int gb = (N_NODES + 3) / 4;             // 2500 blocks, 4 nodes x 64 lanes
    const int mb = (NROWS + MROWS - 1) / MROWS;

    // ---- CSR build + fp16 convert
    const int zn = (int)(((char*)(cnt + N_NODES) - (char*)deg) / 16);
    zero_kernel<<<(zn + 255) / 256, 256, 0, stream>>>((uint4*)deg, zn);
    deg_hist_conv_kernel<<<eb + cb, 256, 0, stream>>>(col, w, deg, cnt, E, eb, x, xh);
    scan_kernel<<<1, 1024, 0, stream>>>(cnt, rowptr, cur, N_NODES);
    fill_kernel<<<eb, 256, 0, stream>>>(row, col, w, deg, cur, edge_s, E);

    // ---- layer 1: 64-lane gather -> aggx, tiled MLP -> y2h
    gather64_kernel<false><<<gb, 256, 0, stream>>>(rowptr, edge_s, xh, nullptr, aggx, N_NODES);
    mlp_kernel<<<mb, 128, 0, stream>>>(aggx, W1, b1, W2, y2h);

    // ---- layer 2: 64-lane gather with fused tanh(acc + b2)
    gather64_kernel<true><<<gb, 256, 0, stream>>>(rowptr, edge_s, y2h, b2, out, N_NODES);
}

// Round 10
// 137.081 us; speedup vs baseline: 9.0646x; 1.2093x over previous
//
#include <hip/hip_runtime.h>
#include <hip/hip_fp16.h>

#define T_DIM   12
#define N_NODES 10000
#define F_IN    32
#define H_DIM   64
#define NCH     3            // t-chunks
#define TC      4            // timesteps per chunk
#define CHROW   (TC * F_IN)  // fp16/fp32 elements per node per chunk = 128
#define NGRP    (N_NODES / 16)
#define NTASK   (NCH * NGRP)
#define NROWS   (NCH * N_NODES * TC)  // 120000 (n,t) rows
#define MROWS   128                   // rows per mlp block

#define CNT_SHIFT 40
#define FIX_SCALE 1048576.0f          // 2^20
#define FIX_MASK  ((1ull << CNT_SHIFT) - 1)

// ------------------------------------------------ zero packed deg/cnt
__global__ void zero_kernel(uint4* __restrict__ p, int n16) {
    int i = blockIdx.x * blockDim.x + threadIdx.x;
    if (i < n16) p[i] = make_uint4(0, 0, 0, 0);
}

// ------------------------------------------------ fused: packed degree+count atomic (one 64-bit
// atomic per edge; return value = within-bucket position) and x fp32 -> xh fp16 chunked convert
__global__ void deg_hist_conv_kernel(const int* __restrict__ col,
                                     const float* __restrict__ w,
                                     unsigned long long* __restrict__ packed,
                                     unsigned int* __restrict__ posE, int E, int eb,
                                     const float* __restrict__ x,
                                     __half* __restrict__ xh) {
    int b = blockIdx.x;
    if (b < eb) {
        int e = b * 256 + threadIdx.x;
        if (e >= E) return;
        int c = col[e];
        unsigned long long fx = (unsigned long long)(w[e] * FIX_SCALE + 0.5f);
        unsigned long long old = atomicAdd(&packed[c], (1ull << CNT_SHIFT) | fx);
        posE[e] = (unsigned int)(old >> CNT_SHIFT);
    } else {
        int task = (b - eb) * 4 + (threadIdx.x >> 6);
        if (task >= NTASK) return;
        int l  = threadIdx.x & 63;
        int ch = task / NGRP;
        int ng = task - ch * NGRP;
        int n  = ng * 16 + (l >> 2);
        int t  = ch * TC + (l & 3);
        const float4* xp = (const float4*)(x + ((size_t)t * N_NODES + n) * F_IN);
        union { uint32_t u[16]; uint4 q[4]; } pk;
#pragma unroll
        for (int i = 0; i < 8; i++) {
            float4 v = xp[i];
            __half2 h0 = __floats2half2_rn(v.x, v.y);
            __half2 h1 = __floats2half2_rn(v.z, v.w);
            pk.u[2 * i]     = *(uint32_t*)&h0;
            pk.u[2 * i + 1] = *(uint32_t*)&h1;
        }
        uint4* dp = (uint4*)(xh + ((size_t)ch * N_NODES * TC + ng * 64 + l) * F_IN);
#pragma unroll
        for (int i = 0; i < 4; i++) dp[i] = pk.q[i];
    }
}

// ------------------------------------------------ single-block scan: packed -> rowptr + dinv
__global__ __launch_bounds__(1024) void scan_kernel(const unsigned long long* __restrict__ packed,
                                                    int* __restrict__ rowptr,
                                                    float* __restrict__ dinv, int n) {
    __shared__ int part[1024];
    int tid = threadIdx.x;
    const int per = (n + 1023) / 1024;
    int base = tid * per;
    int s = 0;
    for (int i = 0; i < per; i++) {
        int idx = base + i;
        if (idx < n) {
            unsigned long long p = packed[idx];
            s += (int)(p >> CNT_SHIFT);
            float deg = (float)(p & FIX_MASK) * (1.0f / FIX_SCALE);
            dinv[idx] = deg > 0.f ? rsqrtf(deg) : 0.f;
        }
    }
    part[tid] = s;
    __syncthreads();
    for (int off = 1; off < 1024; off <<= 1) {
        int v = 0;
        if (tid >= off) v = part[tid - off];
        __syncthreads();
        if (tid >= off) part[tid] += v;
        __syncthreads();
    }
    int run = (tid == 0) ? 0 : part[tid - 1];
    for (int i = 0; i < per; i++) {
        int idx = base + i;
        if (idx < n) {
            rowptr[idx] = run;
            run += (int)(packed[idx] >> CNT_SHIFT);
        }
    }
    if (tid == 1023) rowptr[n] = part[1023];
}

// ------------------------------------------------ fill: ATOMIC-FREE bucket placement via posE
__global__ void fill_kernel(const int* __restrict__ row,
                            const int* __restrict__ col,
                            const float* __restrict__ w,
                            const float* __restrict__ dinv,
                            const int* __restrict__ rowptr,
                            const unsigned int* __restrict__ posE,
                            int2* __restrict__ edge_s, int E) {
    int e = blockIdx.x * blockDim.x + threadIdx.x;
    if (e >= E) return;
    int r = row[e];
    int c = col[e];
    float nw = dinv[r] * w[e] * dinv[c];
    int pos = rowptr[c] + (int)posE[e];
    edge_s[pos] = make_int2(r, __float_as_int(nw));
}

// ------------------------------------------------ 64-lane-per-node single-pass gather.
// Two 32-lane halves split the edge list (stride 2), combine via shfl_xor(32).
// TANH=false: write fp32 chunked [ch][n][tc][f]. TANH=true: tanh(acc+bias) -> [t][n][f].
template <bool TANH>
__global__ __launch_bounds__(256) void gather64_kernel(const int* __restrict__ rowptr,
                                                       const int2* __restrict__ edge_s,
                                                       const __half* __restrict__ yh,
                                                       const float* __restrict__ bias,
                                                       float* __restrict__ outp, int n) {
    int c = blockIdx.x * 4 + (threadIdx.x >> 6);
    if (c >= n) return;
    int l    = threadIdx.x & 63;
    int half = l >> 5;
    int l32  = l & 31;          // tc = l32>>3, f-quad = l32&7 -> fp16 offset 4*l32

    int beg = rowptr[c], end = rowptr[c + 1];
    const __half* base = yh + 4 * l32;
    const size_t cstep = (size_t)N_NODES * CHROW;

    float4 a0 = {0.f, 0.f, 0.f, 0.f};
    float4 a1 = {0.f, 0.f, 0.f, 0.f};
    float4 a2 = {0.f, 0.f, 0.f, 0.f};

#pragma unroll 4
    for (int e = beg + half; e < end; e += 2) {
        int2 ed = edge_s[e];
        float nw = __int_as_float(ed.y);
        const __half* p = base + (size_t)ed.x * CHROW;
        uint2 u0 = *(const uint2*)(p);
        uint2 u1 = *(const uint2*)(p + cstep);
        uint2 u2 = *(const uint2*)(p + 2 * cstep);
        float2 f00 = __half22float2(*(__half2*)&u0.x), f01 = __half22float2(*(__half2*)&u0.y);
        float2 f10 = __half22float2(*(__half2*)&u1.x), f11 = __half22float2(*(__half2*)&u1.y);
        float2 f20 = __half22float2(*(__half2*)&u2.x), f21 = __half22float2(*(__half2*)&u2.y);
        a0.x = fmaf(f00.x, nw, a0.x); a0.y = fmaf(f00.y, nw, a0.y);
        a0.z = fmaf(f01.x, nw, a0.z); a0.w = fmaf(f01.y, nw, a0.w);
        a1.x = fmaf(f10.x, nw, a1.x); a1.y = fmaf(f10.y, nw, a1.y);
        a1.z = fmaf(f11.x, nw, a1.z); a1.w = fmaf(f11.y, nw, a1.w);
        a2.x = fmaf(f20.x, nw, a2.x); a2.y = fmaf(f20.y, nw, a2.y);
        a2.z = fmaf(f21.x, nw, a2.z); a2.w = fmaf(f21.y, nw, a2.w);
    }

    a0.x += __shfl_xor(a0.x, 32); a0.y += __shfl_xor(a0.y, 32);
    a0.z += __shfl_xor(a0.z, 32); a0.w += __shfl_xor(a0.w, 32);
    a1.x += __shfl_xor(a1.x, 32); a1.y += __shfl_xor(a1.y, 32);
    a1.z += __shfl_xor(a1.z, 32); a1.w += __shfl_xor(a1.w, 32);
    a2.x += __shfl_xor(a2.x, 32); a2.y += __shfl_xor(a2.y, 32);
    a2.z += __shfl_xor(a2.z, 32); a2.w += __shfl_xor(a2.w, 32);

    if (TANH) {
        float4 b4 = *(const float4*)(bias + 4 * (l32 & 7));
        if (half == 0) {
            a0.x = tanhf(a0.x + b4.x); a0.y = tanhf(a0.y + b4.y);
            a0.z = tanhf(a0.z + b4.z); a0.w = tanhf(a0.w + b4.w);
            a1.x = tanhf(a1.x + b4.x); a1.y = tanhf(a1.y + b4.y);
            a1.z = tanhf(a1.z + b4.z); a1.w = tanhf(a1.w + b4.w);
            int t0 = (l32 >> 3);
            float* op0 = outp + ((size_t)t0 * N_NODES + c) * F_IN + 4 * (l32 & 7);
            *(float4*)(op0)                               = a0;
            *(float4*)(op0 + (size_t)TC * N_NODES * F_IN) = a1;
        } else {
            a2.x = tanhf(a2.x + b4.x); a2.y = tanhf(a2.y + b4.y);
            a2.z = tanhf(a2.z + b4.z); a2.w = tanhf(a2.w + b4.w);
            int t2 = 2 * TC + (l32 >> 3);
            float* op2 = outp + ((size_t)t2 * N_NODES + c) * F_IN + 4 * (l32 & 7);
            *(float4*)op2 = a2;
        }
    } else {
        float* op = outp + (size_t)c * CHROW + 4 * l32;
        const size_t ostep = (size_t)N_NODES * CHROW;
        if (half == 0) {
            *(float4*)(op)         = a0;
            *(float4*)(op + ostep) = a1;
        } else {
            *(float4*)(op + 2 * ostep) = a2;
        }
    }
}

// ------------------------------------------------ fused MLP: register-blocked tile GEMM
__global__ __launch_bounds__(128) void mlp_kernel(const float* __restrict__ aggx,
                                                  const float* __restrict__ W1g,
                                                  const float* __restrict__ b1,
                                                  const float* __restrict__ W2g,
                                                  __half* __restrict__ y2h) {
    __shared__ float W1s[F_IN * H_DIM];
    __shared__ float W2s[H_DIM * F_IN];
    __shared__ float b1s[H_DIM];
    __shared__ float xs[MROWS][F_IN + 1];
    __shared__ float hs[MROWS][H_DIM + 1];

    int tid = threadIdx.x;
    for (int i = tid; i < F_IN * H_DIM; i += 128) { W1s[i] = W1g[i]; W2s[i] = W2g[i]; }
    if (tid < H_DIM) b1s[tid] = b1[tid];

    size_t row0 = (size_t)blockIdx.x * MROWS;
    const float4* src = (const float4*)(aggx + row0 * F_IN);
    for (int i = tid; i < MROWS * (F_IN / 4); i += 128) {
        float4 v = src[i];
        int r = i >> 3, q = (i & 7) * 4;
        xs[r][q + 0] = v.x; xs[r][q + 1] = v.y; xs[r][q + 2] = v.z; xs[r][q + 3] = v.w;
    }
    __syncthreads();

    int rg = tid >> 2;
    int cg = tid & 3;
    int r0 = 4 * rg;

    {
        int c0 = 16 * cg;
        float acc[4][16];
#pragma unroll
        for (int j = 0; j < 16; j++) {
            float b = b1s[c0 + j];
#pragma unroll
            for (int rr = 0; rr < 4; rr++) acc[rr][j] = b;
        }
#pragma unroll 8
        for (int k = 0; k < F_IN; k++) {
            float xr[4];
#pragma unroll
            for (int rr = 0; rr < 4; rr++) xr[rr] = xs[r0 + rr][k];
#pragma unroll
            for (int j = 0; j < 16; j++) {
                float wv = W1s[k * H_DIM + c0 + j];
#pragma unroll
                for (int rr = 0; rr < 4; rr++) acc[rr][j] = fmaf(xr[rr], wv, acc[rr][j]);
            }
        }
#pragma unroll
        for (int rr = 0; rr < 4; rr++)
#pragma unroll
            for (int j = 0; j < 16; j++)
                hs[r0 + rr][c0 + j] = fmaxf(acc[rr][j], 0.f);
    }
    __syncthreads();

    {
        int d0 = 8 * cg;
        float acc[4][8];
#pragma unroll
        for (int rr = 0; rr < 4; rr++)
#pragma unroll
            for (int j = 0; j < 8; j++) acc[rr][j] = 0.f;
#pragma unroll 8
        for (int k = 0; k < H_DIM; k++) {
            float hr[4];
#pragma unroll
            for (int rr = 0; rr < 4; rr++) hr[rr] = hs[r0 + rr][k];
#pragma unroll
            for (int j = 0; j < 8; j++) {
                float wv = W2s[k * F_IN + d0 + j];
#pragma unroll
                for (int rr = 0; rr < 4; rr++) acc[rr][j] = fmaf(hr[rr], wv, acc[rr][j]);
            }
        }
#pragma unroll
        for (int rr = 0; rr < 4; rr++) {
            union { uint32_t u[4]; uint4 q; } pk;
#pragma unroll
            for (int i = 0; i < 4; i++) {
                __half2 hh = __floats2half2_rn(acc[rr][2 * i], acc[rr][2 * i + 1]);
                pk.u[i] = *(uint32_t*)&hh;
            }
            *(uint4*)(y2h + (row0 + r0 + rr) * F_IN + d0) = pk.q;
        }
    }
}

// ----------------------------------------------------------------
extern "C" void kernel_launch(void* const* d_in, const int* in_sizes, int n_in,
                              void* d_out, int out_size, void* d_ws, size_t ws_size,
                              hipStream_t stream) {
    const float* x  = (const float*)d_in[0];
    const int*   ei = (const int*)d_in[1];
    const float* w  = (const float*)d_in[2];
    // d_in[3] = missing_mask (unused)
    const float* W1 = (const float*)d_in[4];
    const float* b1 = (const float*)d_in[5];
    const float* W2 = (const float*)d_in[6];
    const float* b2 = (const float*)d_in[7];
    float* out = (float*)d_out;

    const int E = in_sizes[1] / 2;
    const int* row = ei;
    const int* col = ei + E;

    char* ws = (char*)d_ws;
    size_t off = 0;
    auto alloc = [&](size_t bytes) { void* p = ws + off; off += (bytes + 255) & ~(size_t)255; return p; };
    unsigned long long* packed = (unsigned long long*)alloc(N_NODES * sizeof(unsigned long long));
    unsigned int* posE   = (unsigned int*)alloc((size_t)E * sizeof(unsigned int));
    int*    rowptr = (int*)   alloc((N_NODES + 1) * sizeof(int));
    float*  dinv   = (float*) alloc(N_NODES * sizeof(float));
    int2*   edge_s = (int2*)  alloc((size_t)E * sizeof(int2));
    __half* xh     = (__half*)alloc((size_t)NROWS * F_IN * sizeof(__half));
    __half* y2h    = (__half*)alloc((size_t)(NROWS + 64) * F_IN * sizeof(__half));
    float*  aggx   = (float*) alloc((size_t)(NROWS + 64) * F_IN * sizeof(float));

    const int eb = (E + 255) / 256;
    const int cb = (NTASK + 3) / 4;
    const int gb = (N_NODES + 3) / 4;
    const int mb = (NROWS + MROWS - 1) / MROWS;

    // ---- CSR build + fp16 convert
    const int zn = (N_NODES * 8) / 16;
    zero_kernel<<<(zn + 255) / 256, 256, 0, stream>>>((uint4*)packed, zn);
    deg_hist_conv_kernel<<<eb + cb, 256, 0, stream>>>(col, w, packed, posE, E, eb, x, xh);
    scan_kernel<<<1, 1024, 0, stream>>>(packed, rowptr, dinv, N_NODES);
    fill_kernel<<<eb, 256, 0, stream>>>(row, col, w, dinv, rowptr, posE, edge_s, E);

    // ---- layer 1: 64-lane gather -> aggx, tiled MLP -> y2h
    gather64_kernel<false><<<gb, 256, 0, stream>>>(rowptr, edge_s, xh, nullptr, aggx, N_NODES);
    mlp_kernel<<<mb, 128, 0, stream>>>(aggx, W1, b1, W2, y2h);

    // ---- layer 2: 64-lane gather with fused tanh(acc + b2)
    gather64_kernel<true><<<gb, 256, 0, stream>>>(rowptr, edge_s, y2h, b2, out, N_NODES);
}